// Round 1
// baseline (687.932 us; speedup 1.0000x reference)
//
#include <hip/hip_runtime.h>

#define BB 8
#define SS 1024
#define DD 1024
#define HH 8
#define HD 128
#define GN_EPS 1e-3

// ---------------- K1: per-(h,s) decay scale tables (f64 internally) ----------------
__global__ __launch_bounds__(256) void msr_scales(float* __restrict__ sQ, float* __restrict__ sK) {
    const int h = blockIdx.y;
    const int s = blockIdx.x * 256 + threadIdx.x;
    const double gamma = 1.0 - exp2((double)(-5 - h));
    const double lg = log2(gamma);
    sQ[h * SS + s] = (float)exp2(lg * (double)s);    // gamma^s
    sK[h * SS + s] = (float)exp2(-lg * (double)s);   // gamma^-s
}

// ---------------- K2: Q' = (x_h Wq)*gamma^s, K' = (x_h Wk)*gamma^-t, V = x_h Wv ----
// grid (1024, 3): x = b*128 + h*16 + stile ; y = type (0=Q,1=K,2=V). 64 s-rows/block.
__global__ __launch_bounds__(256) void msr_qkv(
    const float* __restrict__ x,
    const float* __restrict__ Wq, const float* __restrict__ Wk, const float* __restrict__ Wv,
    const float* __restrict__ sQ, const float* __restrict__ sK,
    float* __restrict__ Qo, float* __restrict__ Ko, float* __restrict__ Vo)
{
    const int typ = blockIdx.y;
    const int bid = blockIdx.x;
    const int st = bid & 15, h = (bid >> 4) & 7, b = bid >> 7;
    const int s0 = st * 64;
    const float* __restrict__ W = (typ == 0 ? Wq : (typ == 1 ? Wk : Wv)) + h * HD * HD;
    float* __restrict__ Out = (typ == 0 ? Qo : (typ == 1 ? Ko : Vo));
    const float* scale = (typ == 0) ? sQ : ((typ == 1) ? sK : (const float*)nullptr);

    __shared__ float As[32][68];    // [k][s], padded
    __shared__ float Ws[32][128];   // [k][e]
    const int tid = threadIdx.x;
    const int sg = tid >> 4, eg = tid & 15;   // rows sg*4..+4 ; cols {eg*4..+4, 64+eg*4..+4}
    float acc[4][8];
#pragma unroll
    for (int i = 0; i < 4; i++)
#pragma unroll
        for (int j = 0; j < 8; j++) acc[i][j] = 0.f;

    for (int k0 = 0; k0 < HD; k0 += 32) {
#pragma unroll
        for (int i = 0; i < 2; i++) {
            int fi = i * 256 + tid;
            int s = fi >> 3, k4 = fi & 7;
            float4 v = *(const float4*)&x[(size_t)(b * SS + s0 + s) * DD + h * HD + k0 + k4 * 4];
            As[k4 * 4 + 0][s] = v.x; As[k4 * 4 + 1][s] = v.y;
            As[k4 * 4 + 2][s] = v.z; As[k4 * 4 + 3][s] = v.w;
        }
#pragma unroll
        for (int i = 0; i < 4; i++) {
            int fi = i * 256 + tid;
            int k = fi >> 5, e4 = fi & 31;
            *(float4*)&Ws[k][e4 * 4] = *(const float4*)&W[(k0 + k) * HD + e4 * 4];
        }
        __syncthreads();
#pragma unroll
        for (int k = 0; k < 32; k++) {
            float a[4], w[8];
            *(float4*)a = *(const float4*)&As[k][sg * 4];
            *(float4*)&w[0] = *(const float4*)&Ws[k][eg * 4];
            *(float4*)&w[4] = *(const float4*)&Ws[k][64 + eg * 4];
#pragma unroll
            for (int i = 0; i < 4; i++)
#pragma unroll
                for (int j = 0; j < 8; j++) acc[i][j] += a[i] * w[j];
        }
        __syncthreads();
    }
    const size_t base = ((size_t)(b * HH + h) * SS + s0) * HD;
#pragma unroll
    for (int i = 0; i < 4; i++) {
        int s = sg * 4 + i;
        float sc = scale ? scale[h * SS + s0 + s] : 1.0f;
        float4 o0, o1;
        o0.x = acc[i][0] * sc; o0.y = acc[i][1] * sc; o0.z = acc[i][2] * sc; o0.w = acc[i][3] * sc;
        o1.x = acc[i][4] * sc; o1.y = acc[i][5] * sc; o1.z = acc[i][6] * sc; o1.w = acc[i][7] * sc;
        *(float4*)&Out[base + (size_t)s * HD + eg * 4] = o0;
        *(float4*)&Out[base + (size_t)s * HD + 64 + eg * 4] = o1;
    }
}

// ---------------- K3: Mp[bh,chunk] = K'[t0:t0+256]^T @ V[t0:t0+256]  (split-4) ------
__global__ __launch_bounds__(256) void msr_kv(
    const float* __restrict__ K, const float* __restrict__ V, float* __restrict__ Mp)
{
    const int bid = blockIdx.x;          // bh*4 + chunk
    const int chunk = bid & 3, bh = bid >> 2;
    const int t0 = chunk * 256;
    __shared__ float Ks[16][132];
    __shared__ float Vs[16][132];
    const int tid = threadIdx.x;
    const int dg = tid >> 4, eg = tid & 15;   // d rows dg*8..+8 ; e cols {eg*4..+4, 64+eg*4..+4}
    float acc[8][8];
#pragma unroll
    for (int i = 0; i < 8; i++)
#pragma unroll
        for (int j = 0; j < 8; j++) acc[i][j] = 0.f;
    const float* __restrict__ Kb = K + (size_t)bh * SS * HD;
    const float* __restrict__ Vb = V + (size_t)bh * SS * HD;
    for (int tt = 0; tt < 256; tt += 16) {
#pragma unroll
        for (int i = 0; i < 2; i++) {
            int fi = i * 256 + tid;
            int t = fi >> 5, d4 = fi & 31;
            *(float4*)&Ks[t][d4 * 4] = *(const float4*)&Kb[(size_t)(t0 + tt + t) * HD + d4 * 4];
            *(float4*)&Vs[t][d4 * 4] = *(const float4*)&Vb[(size_t)(t0 + tt + t) * HD + d4 * 4];
        }
        __syncthreads();
#pragma unroll
        for (int t = 0; t < 16; t++) {
            float kv[8], vv[8];
            *(float4*)&kv[0] = *(const float4*)&Ks[t][dg * 8];
            *(float4*)&kv[4] = *(const float4*)&Ks[t][dg * 8 + 4];
            *(float4*)&vv[0] = *(const float4*)&Vs[t][eg * 4];
            *(float4*)&vv[4] = *(const float4*)&Vs[t][64 + eg * 4];
#pragma unroll
            for (int i = 0; i < 8; i++)
#pragma unroll
                for (int j = 0; j < 8; j++) acc[i][j] += kv[i] * vv[j];
        }
        __syncthreads();
    }
    float* __restrict__ Ob = Mp + (size_t)bid * HD * HD;
#pragma unroll
    for (int i = 0; i < 8; i++) {
        int d = dg * 8 + i;
        float4 o0, o1;
        o0.x = acc[i][0]; o0.y = acc[i][1]; o0.z = acc[i][2]; o0.w = acc[i][3];
        o1.x = acc[i][4]; o1.y = acc[i][5]; o1.z = acc[i][6]; o1.w = acc[i][7];
        *(float4*)&Ob[(size_t)d * HD + eg * 4] = o0;
        *(float4*)&Ob[(size_t)d * HD + 64 + eg * 4] = o1;
    }
}

__global__ __launch_bounds__(256) void msr_mred(const float* __restrict__ Mp, float* __restrict__ M) {
    const size_t i = (size_t)blockIdx.x * 256 + threadIdx.x;   // over 64*16384
    const size_t bh = i >> 14, ij = i & 16383;
    const float* p = Mp + (bh * 4) * 16384 + ij;
    M[i] = p[0] + p[16384] + p[2 * 16384] + p[3 * 16384];
}

// ---------------- K4: ret = Q' @ M  (per (b,h), 64 s-rows per block) ----------------
__global__ __launch_bounds__(256) void msr_qm(
    const float* __restrict__ Q, const float* __restrict__ M, float* __restrict__ ret)
{
    const int bid = blockIdx.x;
    const int st = bid & 15, bh = bid >> 4;
    const int s0 = st * 64;
    const float* __restrict__ A = Q + ((size_t)bh * SS + s0) * HD;
    const float* __restrict__ W = M + (size_t)bh * HD * HD;
    float* __restrict__ O = ret + ((size_t)bh * SS + s0) * HD;

    __shared__ float As[32][68];
    __shared__ float Ws[32][128];
    const int tid = threadIdx.x;
    const int sg = tid >> 4, eg = tid & 15;
    float acc[4][8];
#pragma unroll
    for (int i = 0; i < 4; i++)
#pragma unroll
        for (int j = 0; j < 8; j++) acc[i][j] = 0.f;

    for (int k0 = 0; k0 < HD; k0 += 32) {
#pragma unroll
        for (int i = 0; i < 2; i++) {
            int fi = i * 256 + tid;
            int s = fi >> 3, k4 = fi & 7;
            float4 v = *(const float4*)&A[(size_t)s * HD + k0 + k4 * 4];
            As[k4 * 4 + 0][s] = v.x; As[k4 * 4 + 1][s] = v.y;
            As[k4 * 4 + 2][s] = v.z; As[k4 * 4 + 3][s] = v.w;
        }
#pragma unroll
        for (int i = 0; i < 4; i++) {
            int fi = i * 256 + tid;
            int k = fi >> 5, e4 = fi & 31;
            *(float4*)&Ws[k][e4 * 4] = *(const float4*)&W[(k0 + k) * HD + e4 * 4];
        }
        __syncthreads();
#pragma unroll
        for (int k = 0; k < 32; k++) {
            float a[4], w[8];
            *(float4*)a = *(const float4*)&As[k][sg * 4];
            *(float4*)&w[0] = *(const float4*)&Ws[k][eg * 4];
            *(float4*)&w[4] = *(const float4*)&Ws[k][64 + eg * 4];
#pragma unroll
            for (int i = 0; i < 4; i++)
#pragma unroll
                for (int j = 0; j < 8; j++) acc[i][j] += a[i] * w[j];
        }
        __syncthreads();
    }
#pragma unroll
    for (int i = 0; i < 4; i++) {
        int s = sg * 4 + i;
        float4 o0, o1;
        o0.x = acc[i][0]; o0.y = acc[i][1]; o0.z = acc[i][2]; o0.w = acc[i][3];
        o1.x = acc[i][4]; o1.y = acc[i][5]; o1.z = acc[i][6]; o1.w = acc[i][7];
        *(float4*)&O[(size_t)s * HD + eg * 4] = o0;
        *(float4*)&O[(size_t)s * HD + 64 + eg * 4] = o1;
    }
}

// ---------------- K5: group stats (f64 accumulation), split-8 over s ----------------
__global__ __launch_bounds__(256) void msr_stats(const float* __restrict__ ret, double* __restrict__ Sp)
{
    const int bid = blockIdx.x;          // bh*8 + chunk
    const int chunk = bid & 7, bh = bid >> 3;
    const int tid = threadIdx.x;
    const int d = tid & 127, sp = tid >> 7;
    const float* __restrict__ base = ret + (size_t)bh * SS * HD;
    double sm = 0.0, sq = 0.0;
    const int send = chunk * 128 + 128;
    for (int s = chunk * 128 + sp; s < send; s += 2) {
        double v = (double)base[(size_t)s * HD + d];
        sm += v; sq += v * v;
    }
    __shared__ double Lsm[256];
    __shared__ double Lsq[256];
    Lsm[tid] = sm; Lsq[tid] = sq;
    __syncthreads();
    if (tid < 128) { Lsm[tid] += Lsm[tid + 128]; Lsq[tid] += Lsq[tid + 128]; }
    __syncthreads();
    if (tid < 16) {
        double a = 0.0, q = 0.0;
#pragma unroll
        for (int j = 0; j < 8; j++) { a += Lsm[tid * 8 + j]; q += Lsq[tid * 8 + j]; }
        const int b_ = bh >> 3, h_ = bh & 7;
        const int g = b_ * 128 + h_ * 16 + tid;      // global group id (b*128 + within-batch group)
        Sp[(size_t)chunk * 2048 + g * 2 + 0] = a;
        Sp[(size_t)chunk * 2048 + g * 2 + 1] = q;
    }
}

__global__ __launch_bounds__(256) void msr_fstats(const double* __restrict__ Sp,
                                                  float* __restrict__ mean, float* __restrict__ rstd)
{
    const int g = blockIdx.x * 256 + threadIdx.x;
    if (g >= 1024) return;
    double sm = 0.0, sq = 0.0;
#pragma unroll
    for (int c = 0; c < 8; c++) { sm += Sp[(size_t)c * 2048 + g * 2]; sq += Sp[(size_t)c * 2048 + g * 2 + 1]; }
    const double mu = sm / 8192.0;
    double var = sq / 8192.0 - mu * mu;
    if (var < 0.0) var = 0.0;
    mean[g] = (float)mu;
    rstd[g] = (float)(1.0 / sqrt(var + (double)GN_EPS));
}

// ---------------- K6: gating GEMM  out = ReLU(x @ Wg) -------------------------------
__global__ __launch_bounds__(256) void msr_gate(
    const float* __restrict__ x, const float* __restrict__ Wg, float* __restrict__ out)
{
    const int n0 = blockIdx.x * 64, m0 = blockIdx.y * 64;
    __shared__ float As[16][68];
    __shared__ float Bs[16][68];
    const int tid = threadIdx.x;
    const int ty = tid >> 4, tx = tid & 15;
    float acc[4][4];
#pragma unroll
    for (int i = 0; i < 4; i++)
#pragma unroll
        for (int j = 0; j < 4; j++) acc[i][j] = 0.f;
    const int mm = tid >> 2, k4 = tid & 3;
    const int bk = tid >> 4, n4 = tid & 15;

    for (int k0 = 0; k0 < DD; k0 += 16) {
        float4 av = *(const float4*)&x[(size_t)(m0 + mm) * DD + k0 + k4 * 4];
        As[k4 * 4 + 0][mm] = av.x; As[k4 * 4 + 1][mm] = av.y;
        As[k4 * 4 + 2][mm] = av.z; As[k4 * 4 + 3][mm] = av.w;
        *(float4*)&Bs[bk][n4 * 4] = *(const float4*)&Wg[(size_t)(k0 + bk) * DD + n0 + n4 * 4];
        __syncthreads();
#pragma unroll
        for (int k = 0; k < 16; k++) {
            float a[4], bb[4];
            *(float4*)a = *(const float4*)&As[k][ty * 4];
            *(float4*)bb = *(const float4*)&Bs[k][tx * 4];
#pragma unroll
            for (int i = 0; i < 4; i++)
#pragma unroll
                for (int j = 0; j < 4; j++) acc[i][j] += a[i] * bb[j];
        }
        __syncthreads();
    }
#pragma unroll
    for (int i = 0; i < 4; i++) {
        float4 o;
        o.x = fmaxf(acc[i][0], 0.f); o.y = fmaxf(acc[i][1], 0.f);
        o.z = fmaxf(acc[i][2], 0.f); o.w = fmaxf(acc[i][3], 0.f);
        *(float4*)&out[(size_t)(m0 + ty * 4 + i) * DD + n0 + tx * 4] = o;
    }
}

// ---------------- K7: final GEMM  out = (gate ⊙ GN(y)) @ Wo  (GN fused in A-load) ---
__global__ __launch_bounds__(256) void msr_final(
    const float* __restrict__ gate, const float* __restrict__ ret,
    const float* __restrict__ mean, const float* __restrict__ rstd,
    const float* __restrict__ gng, const float* __restrict__ gnb,
    const float* __restrict__ Wo, float* __restrict__ out)
{
    const int n0 = blockIdx.x * 64, m0 = blockIdx.y * 64;
    const int b_ = m0 >> 10;                 // 64-row tile lies within one batch
    __shared__ float As[16][68];
    __shared__ float Bs[16][68];
    const int tid = threadIdx.x;
    const int ty = tid >> 4, tx = tid & 15;
    float acc[4][4];
#pragma unroll
    for (int i = 0; i < 4; i++)
#pragma unroll
        for (int j = 0; j < 4; j++) acc[i][j] = 0.f;
    const int mm = tid >> 2, c4 = tid & 3;
    const int bk = tid >> 4, n4 = tid & 15;
    const int m = m0 + mm, s = m & (SS - 1);

    for (int k0 = 0; k0 < DD; k0 += 16) {
        const int c = k0 + c4 * 4;
        const int h = c >> 7, d = c & 127, g = c >> 3;   // float4 stays inside one group of 8
        float4 wv = *(const float4*)&gate[(size_t)m * DD + c];
        float4 rv = *(const float4*)&ret[((size_t)(b_ * HH + h) * SS + s) * HD + d];
        const float mu = mean[b_ * 128 + g], rs = rstd[b_ * 128 + g];
        float4 gv = *(const float4*)&gng[c];
        float4 bv = *(const float4*)&gnb[c];
        As[c4 * 4 + 0][mm] = wv.x * ((rv.x - mu) * rs * gv.x + bv.x);
        As[c4 * 4 + 1][mm] = wv.y * ((rv.y - mu) * rs * gv.y + bv.y);
        As[c4 * 4 + 2][mm] = wv.z * ((rv.z - mu) * rs * gv.z + bv.z);
        As[c4 * 4 + 3][mm] = wv.w * ((rv.w - mu) * rs * gv.w + bv.w);
        *(float4*)&Bs[bk][n4 * 4] = *(const float4*)&Wo[(size_t)(k0 + bk) * DD + n0 + n4 * 4];
        __syncthreads();
#pragma unroll
        for (int k = 0; k < 16; k++) {
            float a[4], bb[4];
            *(float4*)a = *(const float4*)&As[k][ty * 4];
            *(float4*)bb = *(const float4*)&Bs[k][tx * 4];
#pragma unroll
            for (int i = 0; i < 4; i++)
#pragma unroll
                for (int j = 0; j < 4; j++) acc[i][j] += a[i] * bb[j];
        }
        __syncthreads();
    }
#pragma unroll
    for (int i = 0; i < 4; i++) {
        float4 o;
        o.x = acc[i][0]; o.y = acc[i][1]; o.z = acc[i][2]; o.w = acc[i][3];
        *(float4*)&out[(size_t)(m0 + ty * 4 + i) * DD + n0 + tx * 4] = o;
    }
}

extern "C" void kernel_launch(void* const* d_in, const int* in_sizes, int n_in,
                              void* d_out, int out_size, void* d_ws, size_t ws_size,
                              hipStream_t stream)
{
    const float* x   = (const float*)d_in[0];
    const float* Wq  = (const float*)d_in[1];
    const float* Wk  = (const float*)d_in[2];
    const float* Wv  = (const float*)d_in[3];
    const float* Wg  = (const float*)d_in[4];
    const float* Wo  = (const float*)d_in[5];
    const float* gng = (const float*)d_in[6];
    const float* gnb = (const float*)d_in[7];
    float* out = (float*)d_out;

    char* ws = (char*)d_ws;
    size_t off = 0;
    auto alloc = [&](size_t bytes) -> void* {
        void* p = ws + off;
        off += (bytes + 255) & ~(size_t)255;
        return p;
    };
    const size_t NE = (size_t)BB * HH * SS * HD;   // 8,388,608 elems (== B*S*DIM)
    float*  sQ    = (float*)alloc((size_t)HH * SS * sizeof(float));
    float*  sK    = (float*)alloc((size_t)HH * SS * sizeof(float));
    float*  Qw    = (float*)alloc(NE * sizeof(float));
    float*  Kw    = (float*)alloc(NE * sizeof(float));
    float*  Vw    = (float*)alloc(NE * sizeof(float));
    float*  retw  = (float*)alloc(NE * sizeof(float));
    float*  gatew = (float*)alloc(NE * sizeof(float));
    float*  Mp    = (float*)alloc((size_t)256 * HD * HD * sizeof(float));
    float*  M     = (float*)alloc((size_t)64 * HD * HD * sizeof(float));
    double* Sp    = (double*)alloc((size_t)8 * 1024 * 2 * sizeof(double));
    float*  meanw = (float*)alloc(1024 * sizeof(float));
    float*  rstdw = (float*)alloc(1024 * sizeof(float));

    msr_scales<<<dim3(4, 8), 256, 0, stream>>>(sQ, sK);
    msr_qkv<<<dim3(1024, 3), 256, 0, stream>>>(x, Wq, Wk, Wv, sQ, sK, Qw, Kw, Vw);
    msr_kv<<<dim3(256), 256, 0, stream>>>(Kw, Vw, Mp);
    msr_mred<<<dim3(4096), 256, 0, stream>>>(Mp, M);
    msr_qm<<<dim3(1024), 256, 0, stream>>>(Qw, M, retw);
    msr_stats<<<dim3(512), 256, 0, stream>>>(retw, Sp);
    msr_fstats<<<dim3(4), 256, 0, stream>>>(Sp, meanw, rstdw);
    msr_gate<<<dim3(16, 128), 256, 0, stream>>>(x, Wg, gatew);
    msr_final<<<dim3(16, 128), 256, 0, stream>>>(gatew, retw, meanw, rstdw, gng, gnb, Wo, out);
}

// Round 3
// 214.142 us; speedup vs baseline: 3.2125x; 3.2125x over previous
//
#include <hip/hip_runtime.h>

#define BB 8
#define SS 1024
#define DD 1024
#define HH 8
#define HD 128
#define GN_EPS 1e-3

typedef __attribute__((ext_vector_type(8))) short bf16x8;
typedef __attribute__((ext_vector_type(4))) float f32x4;

#define LDT 40  // LDS row stride in shorts (80B): 2-way bank aliasing only

__device__ __forceinline__ short f2bf(float f) {
    unsigned u = __float_as_uint(f);
    return (short)((u + 0x7fffu + ((u >> 16) & 1u)) >> 16);
}
__device__ __forceinline__ float bf2f(short s) {
    return __uint_as_float(((unsigned)(unsigned short)s) << 16);
}

// ---------------- shared 128x128xK MFMA tile core (bf16 in, f32 acc) ----------------
// A: [128 rows][K] k-contiguous bf16 (already offset to tile row 0)
// B: [128 rows=out cols][K] k-contiguous bf16 (already offset to tile col 0)
// Staging: 2 threads/row, each thread covers 16 shorts (two bf16x8) => full 32-short row.
__device__ __forceinline__ void gemm_tile_128(
    const short* __restrict__ A, size_t ldA,
    const short* __restrict__ B, size_t ldB,
    int K, short* As, short* Bs, f32x4 acc[4][4])
{
    const int tid = threadIdx.x;
    const int lane = tid & 63, wid = tid >> 6;
    const int wr = (wid >> 1) * 64, wc = (wid & 1) * 64;
    const int fr = lane & 15, fk = (lane >> 4) * 8;
    const int srow = tid >> 1, skk = (tid & 1) * 16;
#pragma unroll
    for (int i = 0; i < 4; i++)
#pragma unroll
        for (int j = 0; j < 4; j++) acc[i][j] = (f32x4){0.f, 0.f, 0.f, 0.f};

    for (int k0 = 0; k0 < K; k0 += 32) {
        bf16x8 av0 = *(const bf16x8*)&A[(size_t)srow * ldA + k0 + skk];
        bf16x8 av1 = *(const bf16x8*)&A[(size_t)srow * ldA + k0 + skk + 8];
        bf16x8 bv0 = *(const bf16x8*)&B[(size_t)srow * ldB + k0 + skk];
        bf16x8 bv1 = *(const bf16x8*)&B[(size_t)srow * ldB + k0 + skk + 8];
        __syncthreads();   // previous iteration's reads complete
        *(bf16x8*)&As[srow * LDT + skk]     = av0;
        *(bf16x8*)&As[srow * LDT + skk + 8] = av1;
        *(bf16x8*)&Bs[srow * LDT + skk]     = bv0;
        *(bf16x8*)&Bs[srow * LDT + skk + 8] = bv1;
        __syncthreads();
        bf16x8 af[4], bfv[4];
#pragma unroll
        for (int i = 0; i < 4; i++) af[i] = *(const bf16x8*)&As[(wr + i * 16 + fr) * LDT + fk];
#pragma unroll
        for (int j = 0; j < 4; j++) bfv[j] = *(const bf16x8*)&Bs[(wc + j * 16 + fr) * LDT + fk];
#pragma unroll
        for (int i = 0; i < 4; i++)
#pragma unroll
            for (int j = 0; j < 4; j++)
                acc[i][j] = __builtin_amdgcn_mfma_f32_16x16x32_bf16(af[i], bfv[j], acc[i][j], 0, 0, 0);
    }
}

// ---------------- K1: decay scale tables ----------------
__global__ __launch_bounds__(256) void msr_scales(float* __restrict__ sQ, float* __restrict__ sK) {
    const int h = blockIdx.y;
    const int s = blockIdx.x * 256 + threadIdx.x;
    const double gamma = 1.0 - exp2((double)(-5 - h));
    const double lg = log2(gamma);
    sQ[h * SS + s] = (float)exp2(lg * (double)s);
    sK[h * SS + s] = (float)exp2(-lg * (double)s);
}

// ---------------- cvt: f32 -> bf16 flat (8 elems/thread) ----------------
__global__ __launch_bounds__(256) void cvt_bf16(const float* __restrict__ src, short* __restrict__ dst) {
    const size_t i = ((size_t)blockIdx.x * 256 + threadIdx.x) * 8;
    float4 a = *(const float4*)&src[i];
    float4 b = *(const float4*)&src[i + 4];
    bf16x8 v;
    v[0] = f2bf(a.x); v[1] = f2bf(a.y); v[2] = f2bf(a.z); v[3] = f2bf(a.w);
    v[4] = f2bf(b.x); v[5] = f2bf(b.y); v[6] = f2bf(b.z); v[7] = f2bf(b.w);
    *(bf16x8*)&dst[i] = v;
}

// ---------------- cvt: 1024x1024 f32 -> bf16 transposed ----------------
__global__ __launch_bounds__(256) void cvt_T1024(const float* __restrict__ S, short* __restrict__ D) {
    __shared__ float t[32][33];
    const int bx = blockIdx.x * 32, by = blockIdx.y * 32;
    const int x = threadIdx.x & 31, y0 = threadIdx.x >> 5;
#pragma unroll
    for (int r = 0; r < 32; r += 8) t[y0 + r][x] = S[(size_t)(by + y0 + r) * 1024 + bx + x];
    __syncthreads();
#pragma unroll
    for (int r = 0; r < 32; r += 8) D[(size_t)(bx + y0 + r) * 1024 + by + x] = f2bf(t[x][y0 + r]);
}

// ---------------- cvt: per-head W[h][d][e] -> Wt[typ*8+h][e][d] bf16 ----------------
__global__ __launch_bounds__(256) void cvt_Theads(
    const float* __restrict__ Wq, const float* __restrict__ Wk, const float* __restrict__ Wv,
    short* __restrict__ Wt)
{
    const int ht = blockIdx.y, typ = ht >> 3, h = ht & 7;
    const float* __restrict__ W = (typ == 0 ? Wq : (typ == 1 ? Wk : Wv)) + (size_t)h * HD * HD;
    short* __restrict__ D = Wt + (size_t)ht * HD * HD;
    __shared__ float t[32][33];
    const int bx = (blockIdx.x & 3) * 32, by = (blockIdx.x >> 2) * 32;
    const int x = threadIdx.x & 31, y0 = threadIdx.x >> 5;
#pragma unroll
    for (int r = 0; r < 32; r += 8) t[y0 + r][x] = W[(by + y0 + r) * HD + bx + x];
    __syncthreads();
#pragma unroll
    for (int r = 0; r < 32; r += 8) D[(bx + y0 + r) * HD + by + x] = f2bf(t[x][y0 + r]);
}

// ---------------- cvt: M[bh][d][e] f32 -> Mt[bh][e][d] bf16 ----------------
__global__ __launch_bounds__(256) void cvt_MT(const float* __restrict__ M, short* __restrict__ Mt) {
    const int bh = blockIdx.y;
    const float* __restrict__ S = M + (size_t)bh * HD * HD;
    short* __restrict__ D = Mt + (size_t)bh * HD * HD;
    __shared__ float t[32][33];
    const int bx = (blockIdx.x & 3) * 32, by = (blockIdx.x >> 2) * 32;
    const int x = threadIdx.x & 31, y0 = threadIdx.x >> 5;
#pragma unroll
    for (int r = 0; r < 32; r += 8) t[y0 + r][x] = S[(by + y0 + r) * HD + bx + x];
    __syncthreads();
#pragma unroll
    for (int r = 0; r < 32; r += 8) D[(bx + y0 + r) * HD + by + x] = f2bf(t[x][y0 + r]);
}

// ---------------- QKV: MFMA, epilogue scales. Q'->bf16, K'->f32, V->f32 ----------------
__global__ __launch_bounds__(256) void g_qkv(
    const short* __restrict__ xb, const short* __restrict__ Wt,
    const float* __restrict__ sQ, const float* __restrict__ sK,
    short* __restrict__ Qb, float* __restrict__ Kw, float* __restrict__ Vw)
{
    __shared__ short As[128 * LDT], Bs[128 * LDT];
    f32x4 acc[4][4];
    const int m0 = blockIdx.x * 128;
    const int ht = blockIdx.y, typ = ht >> 3, h = ht & 7;
    gemm_tile_128(xb + (size_t)m0 * DD + h * HD, DD,
                  Wt + (size_t)ht * HD * HD, HD, HD, As, Bs, acc);
    const int tid = threadIdx.x, lane = tid & 63, wid = tid >> 6;
    const int wr = (wid >> 1) * 64, wc = (wid & 1) * 64;
    const int r0 = (lane >> 4) * 4, c = lane & 15;
    const int b = m0 >> 10, s0 = m0 & (SS - 1);
#pragma unroll
    for (int i = 0; i < 4; i++) {
#pragma unroll
        for (int j = 0; j < 4; j++) {
#pragma unroll
            for (int r = 0; r < 4; r++) {
                const int s = s0 + wr + i * 16 + r0 + r;
                const size_t o = ((size_t)((b << 3) + h) * SS + s) * HD + wc + j * 16 + c;
                const float v = acc[i][j][r];
                if (typ == 0)      Qb[o] = f2bf(v * sQ[h * SS + s]);
                else if (typ == 1) Kw[o] = v * sK[h * SS + s];
                else               Vw[o] = v;
            }
        }
    }
}

// ---------------- K3: Mp = K'^T V (split-4, f32 VALU) ----------------
__global__ __launch_bounds__(256) void msr_kv(
    const float* __restrict__ K, const float* __restrict__ V, float* __restrict__ Mp)
{
    const int bid = blockIdx.x;
    const int chunk = bid & 3, bh = bid >> 2;
    const int t0 = chunk * 256;
    __shared__ float Ks[16][132];
    __shared__ float Vs[16][132];
    const int tid = threadIdx.x;
    const int dg = tid >> 4, eg = tid & 15;
    float acc[8][8];
#pragma unroll
    for (int i = 0; i < 8; i++)
#pragma unroll
        for (int j = 0; j < 8; j++) acc[i][j] = 0.f;
    const float* __restrict__ Kb = K + (size_t)bh * SS * HD;
    const float* __restrict__ Vb = V + (size_t)bh * SS * HD;
    for (int tt = 0; tt < 256; tt += 16) {
#pragma unroll
        for (int i = 0; i < 2; i++) {
            int fi = i * 256 + tid;
            int t = fi >> 5, d4 = fi & 31;
            *(float4*)&Ks[t][d4 * 4] = *(const float4*)&Kb[(size_t)(t0 + tt + t) * HD + d4 * 4];
            *(float4*)&Vs[t][d4 * 4] = *(const float4*)&Vb[(size_t)(t0 + tt + t) * HD + d4 * 4];
        }
        __syncthreads();
#pragma unroll
        for (int t = 0; t < 16; t++) {
            float kv[8], vv[8];
            *(float4*)&kv[0] = *(const float4*)&Ks[t][dg * 8];
            *(float4*)&kv[4] = *(const float4*)&Ks[t][dg * 8 + 4];
            *(float4*)&vv[0] = *(const float4*)&Vs[t][eg * 4];
            *(float4*)&vv[4] = *(const float4*)&Vs[t][64 + eg * 4];
#pragma unroll
            for (int i = 0; i < 8; i++)
#pragma unroll
                for (int j = 0; j < 8; j++) acc[i][j] += kv[i] * vv[j];
        }
        __syncthreads();
    }
    float* __restrict__ Ob = Mp + (size_t)bid * HD * HD;
#pragma unroll
    for (int i = 0; i < 8; i++) {
        int d = dg * 8 + i;
        float4 o0, o1;
        o0.x = acc[i][0]; o0.y = acc[i][1]; o0.z = acc[i][2]; o0.w = acc[i][3];
        o1.x = acc[i][4]; o1.y = acc[i][5]; o1.z = acc[i][6]; o1.w = acc[i][7];
        *(float4*)&Ob[(size_t)d * HD + eg * 4] = o0;
        *(float4*)&Ob[(size_t)d * HD + 64 + eg * 4] = o1;
    }
}

__global__ __launch_bounds__(256) void msr_mred(const float* __restrict__ Mp, float* __restrict__ M) {
    const size_t i = (size_t)blockIdx.x * 256 + threadIdx.x;
    const size_t bh = i >> 14, ij = i & 16383;
    const float* p = Mp + (bh * 4) * 16384 + ij;
    M[i] = p[0] + p[16384] + p[2 * 16384] + p[3 * 16384];
}

// ---------------- QM: ret = Q' @ M (MFMA) ----------------
__global__ __launch_bounds__(256) void g_qm(
    const short* __restrict__ Qb, const short* __restrict__ Mt, float* __restrict__ ret)
{
    __shared__ short As[128 * LDT], Bs[128 * LDT];
    f32x4 acc[4][4];
    const int bh = blockIdx.y, m0 = blockIdx.x * 128;
    gemm_tile_128(Qb + ((size_t)bh * SS + m0) * HD, HD,
                  Mt + (size_t)bh * HD * HD, HD, HD, As, Bs, acc);
    const int tid = threadIdx.x, lane = tid & 63, wid = tid >> 6;
    const int wr = (wid >> 1) * 64, wc = (wid & 1) * 64;
    const int r0 = (lane >> 4) * 4, c = lane & 15;
    float* __restrict__ O = ret + ((size_t)bh * SS + m0) * HD;
#pragma unroll
    for (int i = 0; i < 4; i++)
#pragma unroll
        for (int j = 0; j < 4; j++)
#pragma unroll
            for (int r = 0; r < 4; r++)
                O[(size_t)(wr + i * 16 + r0 + r) * HD + wc + j * 16 + c] = acc[i][j][r];
}

// ---------------- group stats (f64) ----------------
__global__ __launch_bounds__(256) void msr_stats(const float* __restrict__ ret, double* __restrict__ Sp)
{
    const int bid = blockIdx.x;
    const int chunk = bid & 7, bh = bid >> 3;
    const int tid = threadIdx.x;
    const int d = tid & 127, sp = tid >> 7;
    const float* __restrict__ base = ret + (size_t)bh * SS * HD;
    double sm = 0.0, sq = 0.0;
    const int send = chunk * 128 + 128;
    for (int s = chunk * 128 + sp; s < send; s += 2) {
        double v = (double)base[(size_t)s * HD + d];
        sm += v; sq += v * v;
    }
    __shared__ double Lsm[256];
    __shared__ double Lsq[256];
    Lsm[tid] = sm; Lsq[tid] = sq;
    __syncthreads();
    if (tid < 128) { Lsm[tid] += Lsm[tid + 128]; Lsq[tid] += Lsq[tid + 128]; }
    __syncthreads();
    if (tid < 16) {
        double a = 0.0, q = 0.0;
#pragma unroll
        for (int j = 0; j < 8; j++) { a += Lsm[tid * 8 + j]; q += Lsq[tid * 8 + j]; }
        const int b_ = bh >> 3, h_ = bh & 7;
        const int g = b_ * 128 + h_ * 16 + tid;
        Sp[(size_t)chunk * 2048 + g * 2 + 0] = a;
        Sp[(size_t)chunk * 2048 + g * 2 + 1] = q;
    }
}

__global__ __launch_bounds__(256) void msr_fstats(const double* __restrict__ Sp,
                                                  float* __restrict__ mean, float* __restrict__ rstd)
{
    const int g = blockIdx.x * 256 + threadIdx.x;
    if (g >= 1024) return;
    double sm = 0.0, sq = 0.0;
#pragma unroll
    for (int c = 0; c < 8; c++) { sm += Sp[(size_t)c * 2048 + g * 2]; sq += Sp[(size_t)c * 2048 + g * 2 + 1]; }
    const double mu = sm / 8192.0;
    double var = sq / 8192.0 - mu * mu;
    if (var < 0.0) var = 0.0;
    mean[g] = (float)mu;
    rstd[g] = (float)(1.0 / sqrt(var + (double)GN_EPS));
}

// ---------------- gate GEMM: gateb = ReLU(xb @ WgT^T) bf16 (MFMA) ----------------
__global__ __launch_bounds__(256) void g_gate(
    const short* __restrict__ xb, const short* __restrict__ WgT, short* __restrict__ gateb)
{
    __shared__ short As[128 * LDT], Bs[128 * LDT];
    f32x4 acc[4][4];
    const int n0 = blockIdx.x * 128, m0 = blockIdx.y * 128;
    gemm_tile_128(xb + (size_t)m0 * DD, DD, WgT + (size_t)n0 * DD, DD, DD, As, Bs, acc);
    const int tid = threadIdx.x, lane = tid & 63, wid = tid >> 6;
    const int wr = (wid >> 1) * 64, wc = (wid & 1) * 64;
    const int r0 = (lane >> 4) * 4, c = lane & 15;
#pragma unroll
    for (int i = 0; i < 4; i++)
#pragma unroll
        for (int j = 0; j < 4; j++)
#pragma unroll
            for (int r = 0; r < 4; r++)
                gateb[(size_t)(m0 + wr + i * 16 + r0 + r) * DD + n0 + wc + j * 16 + c] =
                    f2bf(fmaxf(acc[i][j][r], 0.f));
}

// ---------------- A-prep: Ab = gate ⊙ GN(ret) -> bf16 ----------------
__global__ __launch_bounds__(256) void aprep(
    const short* __restrict__ gateb, const float* __restrict__ ret,
    const float* __restrict__ mean, const float* __restrict__ rstd,
    const float* __restrict__ gng, const float* __restrict__ gnb, short* __restrict__ Ab)
{
    const size_t idx = ((size_t)blockIdx.x * 256 + threadIdx.x) * 4;
    const int m = (int)(idx >> 10), cc = (int)(idx & 1023);
    const int b_ = m >> 10, s = m & (SS - 1), h = cc >> 7, d = cc & 127, g = cc >> 3;
    short4 gv4 = *(const short4*)&gateb[idx];
    float4 rv = *(const float4*)&ret[((size_t)((b_ << 3) + h) * SS + s) * HD + d];
    const float mu = mean[b_ * 128 + g], rs = rstd[b_ * 128 + g];
    float4 gv = *(const float4*)&gng[cc];
    float4 bv = *(const float4*)&gnb[cc];
    short4 o;
    o.x = f2bf(bf2f(gv4.x) * ((rv.x - mu) * rs * gv.x + bv.x));
    o.y = f2bf(bf2f(gv4.y) * ((rv.y - mu) * rs * gv.y + bv.y));
    o.z = f2bf(bf2f(gv4.z) * ((rv.z - mu) * rs * gv.z + bv.z));
    o.w = f2bf(bf2f(gv4.w) * ((rv.w - mu) * rs * gv.w + bv.w));
    *(short4*)&Ab[idx] = o;
}

// ---------------- final GEMM: out = Ab @ WoT^T (MFMA, f32 out) ----------------
__global__ __launch_bounds__(256) void g_final(
    const short* __restrict__ Ab, const short* __restrict__ WoT, float* __restrict__ out)
{
    __shared__ short As[128 * LDT], Bs[128 * LDT];
    f32x4 acc[4][4];
    const int n0 = blockIdx.x * 128, m0 = blockIdx.y * 128;
    gemm_tile_128(Ab + (size_t)m0 * DD, DD, WoT + (size_t)n0 * DD, DD, DD, As, Bs, acc);
    const int tid = threadIdx.x, lane = tid & 63, wid = tid >> 6;
    const int wr = (wid >> 1) * 64, wc = (wid & 1) * 64;
    const int r0 = (lane >> 4) * 4, c = lane & 15;
#pragma unroll
    for (int i = 0; i < 4; i++)
#pragma unroll
        for (int j = 0; j < 4; j++)
#pragma unroll
            for (int r = 0; r < 4; r++)
                out[(size_t)(m0 + wr + i * 16 + r0 + r) * DD + n0 + wc + j * 16 + c] = acc[i][j][r];
}

extern "C" void kernel_launch(void* const* d_in, const int* in_sizes, int n_in,
                              void* d_out, int out_size, void* d_ws, size_t ws_size,
                              hipStream_t stream)
{
    const float* x   = (const float*)d_in[0];
    const float* Wq  = (const float*)d_in[1];
    const float* Wk  = (const float*)d_in[2];
    const float* Wv  = (const float*)d_in[3];
    const float* Wg  = (const float*)d_in[4];
    const float* Wo  = (const float*)d_in[5];
    const float* gng = (const float*)d_in[6];
    const float* gnb = (const float*)d_in[7];
    float* out = (float*)d_out;

    char* ws = (char*)d_ws;
    size_t off = 0;
    auto alloc = [&](size_t bytes) -> void* {
        void* p = ws + off;
        off += (bytes + 255) & ~(size_t)255;
        return p;
    };
    const size_t NE = (size_t)BB * SS * DD;   // 8,388,608
    float*  sQ    = (float*)alloc((size_t)HH * SS * sizeof(float));
    float*  sK    = (float*)alloc((size_t)HH * SS * sizeof(float));
    short*  xb    = (short*)alloc(NE * sizeof(short));
    short*  WgT   = (short*)alloc((size_t)DD * DD * sizeof(short));
    short*  WoT   = (short*)alloc((size_t)DD * DD * sizeof(short));
    short*  Wt    = (short*)alloc((size_t)24 * HD * HD * sizeof(short));
    short*  Qb    = (short*)alloc(NE * sizeof(short));
    float*  Kw    = (float*)alloc(NE * sizeof(float));
    float*  Vw    = (float*)alloc(NE * sizeof(float));
    float*  retw  = (float*)alloc(NE * sizeof(float));
    short*  gateb = (short*)alloc(NE * sizeof(short));
    float*  Mp    = (float*)alloc((size_t)256 * HD * HD * sizeof(float));
    double* Sp    = (double*)alloc((size_t)8 * 1024 * 2 * sizeof(double));
    float*  meanw = (float*)alloc(1024 * sizeof(float));
    float*  rstdw = (float*)alloc(1024 * sizeof(float));
    // overlays (lifetimes disjoint):
    short*  Ab    = (short*)Kw;                       // Kw dead after msr_kv; Ab written by aprep
    float*  M     = (float*)Vw;                       // Vw dead after msr_kv; M = 4.2MB
    short*  Mt    = (short*)((char*)Vw + (8u << 20)); // Mt = 2.1MB at Vw+8MB (no overlap with M)

    msr_scales<<<dim3(4, 8), 256, 0, stream>>>(sQ, sK);
    cvt_bf16<<<dim3(4096), 256, 0, stream>>>(x, xb);
    cvt_T1024<<<dim3(32, 32), 256, 0, stream>>>(Wg, WgT);
    cvt_T1024<<<dim3(32, 32), 256, 0, stream>>>(Wo, WoT);
    cvt_Theads<<<dim3(16, 24), 256, 0, stream>>>(Wq, Wk, Wv, Wt);
    g_qkv<<<dim3(64, 24), 256, 0, stream>>>(xb, Wt, sQ, sK, Qb, Kw, Vw);
    msr_kv<<<dim3(256), 256, 0, stream>>>(Kw, Vw, Mp);
    msr_mred<<<dim3(4096), 256, 0, stream>>>(Mp, M);
    cvt_MT<<<dim3(16, 64), 256, 0, stream>>>(M, Mt);
    g_qm<<<dim3(8, 64), 256, 0, stream>>>(Qb, Mt, retw);
    msr_stats<<<dim3(512), 256, 0, stream>>>(retw, Sp);
    msr_fstats<<<dim3(4), 256, 0, stream>>>(Sp, meanw, rstdw);
    g_gate<<<dim3(8, 64), 256, 0, stream>>>(xb, WgT, gateb);
    aprep<<<dim3(8192), 256, 0, stream>>>(gateb, retw, meanw, rstdw, gng, gnb, Ab);
    g_final<<<dim3(8, 64), 256, 0, stream>>>(Ab, WoT, out);
}

// Round 4
// 168.451 us; speedup vs baseline: 4.0839x; 1.2712x over previous
//
#include <hip/hip_runtime.h>

#define BB 8
#define SS 1024
#define DD 1024
#define HH 8
#define HD 128
#define GN_EPS 1e-3

typedef __attribute__((ext_vector_type(8))) short bf16x8;
typedef __attribute__((ext_vector_type(4))) float f32x4;

#define LDT 40  // LDS row stride in shorts (80B): 2-way bank aliasing only

__device__ __forceinline__ short f2bf(float f) {
    unsigned u = __float_as_uint(f);
    return (short)((u + 0x7fffu + ((u >> 16) & 1u)) >> 16);
}
__device__ __forceinline__ float bf2f(short s) {
    return __uint_as_float(((unsigned)(unsigned short)s) << 16);
}

// ---------------- shared 128x128xK MFMA tile core (bf16 in, f32 acc) ----------------
// A: [128 rows][K] k-contiguous bf16 ; B: [128 cols][K] k-contiguous bf16
__device__ __forceinline__ void gemm_tile_128(
    const short* __restrict__ A, size_t ldA,
    const short* __restrict__ B, size_t ldB,
    int K, short* As, short* Bs, f32x4 acc[4][4])
{
    const int tid = threadIdx.x;
    const int lane = tid & 63, wid = tid >> 6;
    const int wr = (wid >> 1) * 64, wc = (wid & 1) * 64;
    const int fr = lane & 15, fk = (lane >> 4) * 8;
    const int srow = tid >> 1, skk = (tid & 1) * 16;
#pragma unroll
    for (int i = 0; i < 4; i++)
#pragma unroll
        for (int j = 0; j < 4; j++) acc[i][j] = (f32x4){0.f, 0.f, 0.f, 0.f};

    for (int k0 = 0; k0 < K; k0 += 32) {
        bf16x8 av0 = *(const bf16x8*)&A[(size_t)srow * ldA + k0 + skk];
        bf16x8 av1 = *(const bf16x8*)&A[(size_t)srow * ldA + k0 + skk + 8];
        bf16x8 bv0 = *(const bf16x8*)&B[(size_t)srow * ldB + k0 + skk];
        bf16x8 bv1 = *(const bf16x8*)&B[(size_t)srow * ldB + k0 + skk + 8];
        __syncthreads();   // previous iteration's reads complete
        *(bf16x8*)&As[srow * LDT + skk]     = av0;
        *(bf16x8*)&As[srow * LDT + skk + 8] = av1;
        *(bf16x8*)&Bs[srow * LDT + skk]     = bv0;
        *(bf16x8*)&Bs[srow * LDT + skk + 8] = bv1;
        __syncthreads();
        bf16x8 af[4], bfv[4];
#pragma unroll
        for (int i = 0; i < 4; i++) af[i] = *(const bf16x8*)&As[(wr + i * 16 + fr) * LDT + fk];
#pragma unroll
        for (int j = 0; j < 4; j++) bfv[j] = *(const bf16x8*)&Bs[(wc + j * 16 + fr) * LDT + fk];
#pragma unroll
        for (int i = 0; i < 4; i++)
#pragma unroll
            for (int j = 0; j < 4; j++)
                acc[i][j] = __builtin_amdgcn_mfma_f32_16x16x32_bf16(af[i], bfv[j], acc[i][j], 0, 0, 0);
    }
}

// ---------------- K1: decay scale tables ----------------
__global__ __launch_bounds__(256) void msr_scales(float* __restrict__ sQ, float* __restrict__ sK) {
    const int h = blockIdx.y;
    const int s = blockIdx.x * 256 + threadIdx.x;
    const double gamma = 1.0 - exp2((double)(-5 - h));
    const double lg = log2(gamma);
    sQ[h * SS + s] = (float)exp2(lg * (double)s);
    sK[h * SS + s] = (float)exp2(-lg * (double)s);
}

// ---------------- cvt: f32 -> bf16 flat (8 elems/thread) ----------------
__global__ __launch_bounds__(256) void cvt_bf16(const float* __restrict__ src, short* __restrict__ dst) {
    const size_t i = ((size_t)blockIdx.x * 256 + threadIdx.x) * 8;
    float4 a = *(const float4*)&src[i];
    float4 b = *(const float4*)&src[i + 4];
    bf16x8 v;
    v[0] = f2bf(a.x); v[1] = f2bf(a.y); v[2] = f2bf(a.z); v[3] = f2bf(a.w);
    v[4] = f2bf(b.x); v[5] = f2bf(b.y); v[6] = f2bf(b.z); v[7] = f2bf(b.w);
    *(bf16x8*)&dst[i] = v;
}

// ---------------- cvt: 1024x1024 f32 -> bf16 transposed ----------------
__global__ __launch_bounds__(256) void cvt_T1024(const float* __restrict__ S, short* __restrict__ D) {
    __shared__ float t[32][33];
    const int bx = blockIdx.x * 32, by = blockIdx.y * 32;
    const int x = threadIdx.x & 31, y0 = threadIdx.x >> 5;
#pragma unroll
    for (int r = 0; r < 32; r += 8) t[y0 + r][x] = S[(size_t)(by + y0 + r) * 1024 + bx + x];
    __syncthreads();
#pragma unroll
    for (int r = 0; r < 32; r += 8) D[(size_t)(bx + y0 + r) * 1024 + by + x] = f2bf(t[x][y0 + r]);
}

// ---------------- cvt: per-head W[h][d][e] -> Wt[typ*8+h][e][d] bf16 ----------------
__global__ __launch_bounds__(256) void cvt_Theads(
    const float* __restrict__ Wq, const float* __restrict__ Wk, const float* __restrict__ Wv,
    short* __restrict__ Wt)
{
    const int ht = blockIdx.y, typ = ht >> 3, h = ht & 7;
    const float* __restrict__ W = (typ == 0 ? Wq : (typ == 1 ? Wk : Wv)) + (size_t)h * HD * HD;
    short* __restrict__ D = Wt + (size_t)ht * HD * HD;
    __shared__ float t[32][33];
    const int bx = (blockIdx.x & 3) * 32, by = (blockIdx.x >> 2) * 32;
    const int x = threadIdx.x & 31, y0 = threadIdx.x >> 5;
#pragma unroll
    for (int r = 0; r < 32; r += 8) t[y0 + r][x] = W[(by + y0 + r) * HD + bx + x];
    __syncthreads();
#pragma unroll
    for (int r = 0; r < 32; r += 8) D[(bx + y0 + r) * HD + by + x] = f2bf(t[x][y0 + r]);
}

// ---------------- QKV: MFMA. Q'->bf16 [bh][s][d]; K'->bf16 [bh][d][t]; V->bf16 [bh][e][t]
__global__ __launch_bounds__(256) void g_qkv(
    const short* __restrict__ xb, const short* __restrict__ Wt,
    const float* __restrict__ sQ, const float* __restrict__ sK,
    short* __restrict__ Qb, short* __restrict__ Ktb, short* __restrict__ Vtb)
{
    __shared__ short As[128 * LDT], Bs[128 * LDT];
    f32x4 acc[4][4];
    const int m0 = blockIdx.x * 128;
    const int ht = blockIdx.y, typ = ht >> 3, h = ht & 7;
    gemm_tile_128(xb + (size_t)m0 * DD + h * HD, DD,
                  Wt + (size_t)ht * HD * HD, HD, HD, As, Bs, acc);
    const int tid = threadIdx.x, lane = tid & 63, wid = tid >> 6;
    const int wr = (wid >> 1) * 64, wc = (wid & 1) * 64;
    const int r0 = (lane >> 4) * 4, c = lane & 15;
    const int b = m0 >> 10, s0 = m0 & (SS - 1);
    const int bh = (b << 3) + h;
    if (typ == 0) {
        // Q' row-major bf16, scaled by gamma^s
#pragma unroll
        for (int i = 0; i < 4; i++)
#pragma unroll
            for (int j = 0; j < 4; j++)
#pragma unroll
                for (int r = 0; r < 4; r++) {
                    const int s = s0 + wr + i * 16 + r0 + r;
                    Qb[((size_t)bh * SS + s) * HD + wc + j * 16 + c] =
                        f2bf(acc[i][j][r] * sQ[h * SS + s]);
                }
    } else if (typ == 1) {
        // K' transposed: Ktb[bh][d][t], scaled by gamma^-t; short4 over 4 consecutive t
        short* __restrict__ Ob = Ktb + (size_t)bh * HD * SS;
#pragma unroll
        for (int i = 0; i < 4; i++)
#pragma unroll
            for (int j = 0; j < 4; j++) {
                const int tb = s0 + wr + i * 16 + r0;
                const int d = wc + j * 16 + c;
                short4 o;
                o.x = f2bf(acc[i][j][0] * sK[h * SS + tb + 0]);
                o.y = f2bf(acc[i][j][1] * sK[h * SS + tb + 1]);
                o.z = f2bf(acc[i][j][2] * sK[h * SS + tb + 2]);
                o.w = f2bf(acc[i][j][3] * sK[h * SS + tb + 3]);
                *(short4*)&Ob[(size_t)d * SS + tb] = o;
            }
    } else {
        // V transposed: Vtb[bh][e][t]
        short* __restrict__ Ob = Vtb + (size_t)bh * HD * SS;
#pragma unroll
        for (int i = 0; i < 4; i++)
#pragma unroll
            for (int j = 0; j < 4; j++) {
                const int tb = s0 + wr + i * 16 + r0;
                const int e = wc + j * 16 + c;
                short4 o;
                o.x = f2bf(acc[i][j][0]); o.y = f2bf(acc[i][j][1]);
                o.z = f2bf(acc[i][j][2]); o.w = f2bf(acc[i][j][3]);
                *(short4*)&Ob[(size_t)e * SS + tb] = o;
            }
    }
}

// ---------------- KV: Mp[bid][e][d] = V_chunk^T K'_chunk (MFMA, split-4 over t) -----
__global__ __launch_bounds__(256) void g_kv(
    const short* __restrict__ Vtb, const short* __restrict__ Ktb, float* __restrict__ Mp)
{
    __shared__ short As[128 * LDT], Bs[128 * LDT];
    f32x4 acc[4][4];
    const int bid = blockIdx.x;
    const int chunk = bid & 3, bh = bid >> 2;
    gemm_tile_128(Vtb + (size_t)bh * HD * SS + chunk * 256, SS,
                  Ktb + (size_t)bh * HD * SS + chunk * 256, SS, 256, As, Bs, acc);
    const int tid = threadIdx.x, lane = tid & 63, wid = tid >> 6;
    const int wr = (wid >> 1) * 64, wc = (wid & 1) * 64;
    const int r0 = (lane >> 4) * 4, c = lane & 15;
    float* __restrict__ Ob = Mp + (size_t)bid * HD * HD;
#pragma unroll
    for (int i = 0; i < 4; i++)
#pragma unroll
        for (int j = 0; j < 4; j++)
#pragma unroll
            for (int r = 0; r < 4; r++)
                Ob[(size_t)(wr + i * 16 + r0 + r) * HD + wc + j * 16 + c] = acc[i][j][r];
}

// ---------------- reduce 4 chunks + cvt: Mtb[bh][e][d] bf16 ----------------
__global__ __launch_bounds__(256) void g_mredcvt(const float* __restrict__ Mp, short* __restrict__ Mtb) {
    const size_t i = ((size_t)blockIdx.x * 256 + threadIdx.x) * 8;   // over 64*16384
    const size_t bh = i >> 14, ij = i & 16383;
    const float* p = Mp + (bh * 4) * 16384 + ij;
    float s[8];
#pragma unroll
    for (int q = 0; q < 8; q++) s[q] = 0.f;
#pragma unroll
    for (int cth = 0; cth < 4; cth++) {
        float4 a = *(const float4*)&p[cth * 16384];
        float4 b = *(const float4*)&p[cth * 16384 + 4];
        s[0] += a.x; s[1] += a.y; s[2] += a.z; s[3] += a.w;
        s[4] += b.x; s[5] += b.y; s[6] += b.z; s[7] += b.w;
    }
    bf16x8 v;
#pragma unroll
    for (int q = 0; q < 8; q++) v[q] = f2bf(s[q]);
    *(bf16x8*)&Mtb[i] = v;
}

// ---------------- QM: retb[bh][s][e] = Q' @ M (MFMA, bf16 out) ----------------
__global__ __launch_bounds__(256) void g_qm(
    const short* __restrict__ Qb, const short* __restrict__ Mtb, short* __restrict__ retb)
{
    __shared__ short As[128 * LDT], Bs[128 * LDT];
    f32x4 acc[4][4];
    const int bh = blockIdx.y, m0 = blockIdx.x * 128;
    gemm_tile_128(Qb + ((size_t)bh * SS + m0) * HD, HD,
                  Mtb + (size_t)bh * HD * HD, HD, HD, As, Bs, acc);
    const int tid = threadIdx.x, lane = tid & 63, wid = tid >> 6;
    const int wr = (wid >> 1) * 64, wc = (wid & 1) * 64;
    const int r0 = (lane >> 4) * 4, c = lane & 15;
    short* __restrict__ O = retb + ((size_t)bh * SS + m0) * HD;
#pragma unroll
    for (int i = 0; i < 4; i++)
#pragma unroll
        for (int j = 0; j < 4; j++)
#pragma unroll
            for (int r = 0; r < 4; r++)
                O[(size_t)(wr + i * 16 + r0 + r) * HD + wc + j * 16 + c] = f2bf(acc[i][j][r]);
}

// ---------------- group stats (f64 accumulation) from bf16 ret ----------------
__global__ __launch_bounds__(256) void msr_stats(const short* __restrict__ retb, double* __restrict__ Sp)
{
    const int bid = blockIdx.x;
    const int chunk = bid & 7, bh = bid >> 3;
    const int tid = threadIdx.x;
    const int d = tid & 127, sp = tid >> 7;
    const short* __restrict__ base = retb + (size_t)bh * SS * HD;
    double sm = 0.0, sq = 0.0;
    const int send = chunk * 128 + 128;
    for (int s = chunk * 128 + sp; s < send; s += 2) {
        double v = (double)bf2f(base[(size_t)s * HD + d]);
        sm += v; sq += v * v;
    }
    __shared__ double Lsm[256];
    __shared__ double Lsq[256];
    Lsm[tid] = sm; Lsq[tid] = sq;
    __syncthreads();
    if (tid < 128) { Lsm[tid] += Lsm[tid + 128]; Lsq[tid] += Lsq[tid + 128]; }
    __syncthreads();
    if (tid < 16) {
        double a = 0.0, q = 0.0;
#pragma unroll
        for (int j = 0; j < 8; j++) { a += Lsm[tid * 8 + j]; q += Lsq[tid * 8 + j]; }
        const int b_ = bh >> 3, h_ = bh & 7;
        const int g = b_ * 128 + h_ * 16 + tid;
        Sp[(size_t)chunk * 2048 + g * 2 + 0] = a;
        Sp[(size_t)chunk * 2048 + g * 2 + 1] = q;
    }
}

__global__ __launch_bounds__(256) void msr_fstats(const double* __restrict__ Sp,
                                                  float* __restrict__ mean, float* __restrict__ rstd)
{
    const int g = blockIdx.x * 256 + threadIdx.x;
    if (g >= 1024) return;
    double sm = 0.0, sq = 0.0;
#pragma unroll
    for (int c = 0; c < 8; c++) { sm += Sp[(size_t)c * 2048 + g * 2]; sq += Sp[(size_t)c * 2048 + g * 2 + 1]; }
    const double mu = sm / 8192.0;
    double var = sq / 8192.0 - mu * mu;
    if (var < 0.0) var = 0.0;
    mean[g] = (float)mu;
    rstd[g] = (float)(1.0 / sqrt(var + (double)GN_EPS));
}

// ---------------- gate GEMM: gateb = ReLU(xb @ WgT^T) bf16 (MFMA) ----------------
__global__ __launch_bounds__(256) void g_gate(
    const short* __restrict__ xb, const short* __restrict__ WgT, short* __restrict__ gateb)
{
    __shared__ short As[128 * LDT], Bs[128 * LDT];
    f32x4 acc[4][4];
    const int n0 = blockIdx.x * 128, m0 = blockIdx.y * 128;
    gemm_tile_128(xb + (size_t)m0 * DD, DD, WgT + (size_t)n0 * DD, DD, DD, As, Bs, acc);
    const int tid = threadIdx.x, lane = tid & 63, wid = tid >> 6;
    const int wr = (wid >> 1) * 64, wc = (wid & 1) * 64;
    const int r0 = (lane >> 4) * 4, c = lane & 15;
#pragma unroll
    for (int i = 0; i < 4; i++)
#pragma unroll
        for (int j = 0; j < 4; j++)
#pragma unroll
            for (int r = 0; r < 4; r++)
                gateb[(size_t)(m0 + wr + i * 16 + r0 + r) * DD + n0 + wc + j * 16 + c] =
                    f2bf(fmaxf(acc[i][j][r], 0.f));
}

// ---------------- A-prep: Ab = gate ⊙ GN(ret) -> bf16 ----------------
__global__ __launch_bounds__(256) void aprep(
    const short* __restrict__ gateb, const short* __restrict__ retb,
    const float* __restrict__ mean, const float* __restrict__ rstd,
    const float* __restrict__ gng, const float* __restrict__ gnb, short* __restrict__ Ab)
{
    const size_t idx = ((size_t)blockIdx.x * 256 + threadIdx.x) * 4;
    const int m = (int)(idx >> 10), cc = (int)(idx & 1023);
    const int b_ = m >> 10, s = m & (SS - 1), h = cc >> 7, d = cc & 127, g = cc >> 3;
    short4 gv4 = *(const short4*)&gateb[idx];
    short4 rv4 = *(const short4*)&retb[((size_t)((b_ << 3) + h) * SS + s) * HD + d];
    const float mu = mean[b_ * 128 + g], rs = rstd[b_ * 128 + g];
    float4 gv = *(const float4*)&gng[cc];
    float4 bv = *(const float4*)&gnb[cc];
    short4 o;
    o.x = f2bf(bf2f(gv4.x) * ((bf2f(rv4.x) - mu) * rs * gv.x + bv.x));
    o.y = f2bf(bf2f(gv4.y) * ((bf2f(rv4.y) - mu) * rs * gv.y + bv.y));
    o.z = f2bf(bf2f(gv4.z) * ((bf2f(rv4.z) - mu) * rs * gv.z + bv.z));
    o.w = f2bf(bf2f(gv4.w) * ((bf2f(rv4.w) - mu) * rs * gv.w + bv.w));
    *(short4*)&Ab[idx] = o;
}

// ---------------- final GEMM: out = Ab @ WoT^T (MFMA, f32 out) ----------------
__global__ __launch_bounds__(256) void g_final(
    const short* __restrict__ Ab, const short* __restrict__ WoT, float* __restrict__ out)
{
    __shared__ short As[128 * LDT], Bs[128 * LDT];
    f32x4 acc[4][4];
    const int n0 = blockIdx.x * 128, m0 = blockIdx.y * 128;
    gemm_tile_128(Ab + (size_t)m0 * DD, DD, WoT + (size_t)n0 * DD, DD, DD, As, Bs, acc);
    const int tid = threadIdx.x, lane = tid & 63, wid = tid >> 6;
    const int wr = (wid >> 1) * 64, wc = (wid & 1) * 64;
    const int r0 = (lane >> 4) * 4, c = lane & 15;
#pragma unroll
    for (int i = 0; i < 4; i++)
#pragma unroll
        for (int j = 0; j < 4; j++)
#pragma unroll
            for (int r = 0; r < 4; r++)
                out[(size_t)(m0 + wr + i * 16 + r0 + r) * DD + n0 + wc + j * 16 + c] = acc[i][j][r];
}

extern "C" void kernel_launch(void* const* d_in, const int* in_sizes, int n_in,
                              void* d_out, int out_size, void* d_ws, size_t ws_size,
                              hipStream_t stream)
{
    const float* x   = (const float*)d_in[0];
    const float* Wq  = (const float*)d_in[1];
    const float* Wk  = (const float*)d_in[2];
    const float* Wv  = (const float*)d_in[3];
    const float* Wg  = (const float*)d_in[4];
    const float* Wo  = (const float*)d_in[5];
    const float* gng = (const float*)d_in[6];
    const float* gnb = (const float*)d_in[7];
    float* out = (float*)d_out;

    char* ws = (char*)d_ws;
    size_t off = 0;
    auto alloc = [&](size_t bytes) -> void* {
        void* p = ws + off;
        off += (bytes + 255) & ~(size_t)255;
        return p;
    };
    const size_t NE = (size_t)BB * SS * DD;   // 8,388,608
    float*  sQ    = (float*)alloc((size_t)HH * SS * sizeof(float));
    float*  sK    = (float*)alloc((size_t)HH * SS * sizeof(float));
    short*  xb    = (short*)alloc(NE * sizeof(short));
    short*  WgT   = (short*)alloc((size_t)DD * DD * sizeof(short));
    short*  WoT   = (short*)alloc((size_t)DD * DD * sizeof(short));
    short*  Wt    = (short*)alloc((size_t)24 * HD * HD * sizeof(short));
    short*  Qb    = (short*)alloc(NE * sizeof(short));
    short*  Ktb   = (short*)alloc(NE * sizeof(short));
    short*  Vtb   = (short*)alloc(NE * sizeof(short));
    short*  retb  = (short*)alloc(NE * sizeof(short));
    short*  gateb = (short*)alloc(NE * sizeof(short));
    short*  Ab    = (short*)alloc(NE * sizeof(short));
    float*  Mp    = (float*)alloc((size_t)256 * HD * HD * sizeof(float));
    short*  Mtb   = (short*)alloc((size_t)64 * HD * HD * sizeof(short));
    double* Sp    = (double*)alloc((size_t)8 * 1024 * 2 * sizeof(double));
    float*  meanw = (float*)alloc(1024 * sizeof(float));
    float*  rstdw = (float*)alloc(1024 * sizeof(float));

    msr_scales<<<dim3(4, 8), 256, 0, stream>>>(sQ, sK);
    cvt_bf16<<<dim3(4096), 256, 0, stream>>>(x, xb);
    cvt_T1024<<<dim3(32, 32), 256, 0, stream>>>(Wg, WgT);
    cvt_T1024<<<dim3(32, 32), 256, 0, stream>>>(Wo, WoT);
    cvt_Theads<<<dim3(16, 24), 256, 0, stream>>>(Wq, Wk, Wv, Wt);
    g_qkv<<<dim3(64, 24), 256, 0, stream>>>(xb, Wt, sQ, sK, Qb, Ktb, Vtb);
    g_kv<<<dim3(256), 256, 0, stream>>>(Vtb, Ktb, Mp);
    g_mredcvt<<<dim3(512), 256, 0, stream>>>(Mp, Mtb);
    g_qm<<<dim3(8, 64), 256, 0, stream>>>(Qb, Mtb, retb);
    msr_stats<<<dim3(512), 256, 0, stream>>>(retb, Sp);
    msr_fstats<<<dim3(4), 256, 0, stream>>>(Sp, meanw, rstdw);
    g_gate<<<dim3(8, 64), 256, 0, stream>>>(xb, WgT, gateb);
    aprep<<<dim3(8192), 256, 0, stream>>>(gateb, retb, meanw, rstdw, gng, gnb, Ab);
    g_final<<<dim3(8, 64), 256, 0, stream>>>(Ab, WoT, out);
}

// Round 5
// 164.807 us; speedup vs baseline: 4.1742x; 1.0221x over previous
//
#include <hip/hip_runtime.h>

#define BB 8
#define SS 1024
#define DD 1024
#define HH 8
#define HD 128
#define GN_EPS 1e-3

typedef __attribute__((ext_vector_type(8))) short bf16x8;
typedef __attribute__((ext_vector_type(4))) float f32x4;

__device__ __forceinline__ short f2bf(float f) {
    unsigned u = __float_as_uint(f);
    return (short)((u + 0x7fffu + ((u >> 16) & 1u)) >> 16);
}
__device__ __forceinline__ float bf2f(short s) {
    return __uint_as_float(((unsigned)(unsigned short)s) << 16);
}

__device__ __forceinline__ void gload16(const void* g, void* l) {
    __builtin_amdgcn_global_load_lds((const __attribute__((address_space(1))) void*)g,
                                     (__attribute__((address_space(3))) void*)l, 16, 0, 0);
}

// ---- stage one 128x32-short tile (8 KB) via global_load_lds, linear row-major LDS ----
// wave w covers LDS segments {2w, 2w+1}; segment = 16 rows; lane l -> row seg*16+(l>>2),
// 16B chunk (l&3)*8 shorts. LDS dest is wave-uniform base; HW adds lane*16B.
__device__ __forceinline__ void stage_tile(const short* __restrict__ G, size_t ld, int k0,
                                           short* lds, int wid, int lane) {
#pragma unroll
    for (int i = 0; i < 2; i++) {
        const int seg = wid * 2 + i;
        const int row = seg * 16 + (lane >> 2);
        gload16(G + (size_t)row * ld + k0 + (lane & 3) * 8, lds + seg * 512);
    }
}

// ---------------- 128x128xK MFMA tile core: global_load_lds + LDS double-buffer ------
// A: [128 rows][K] k-contiguous bf16 ; B: [128 cols][K] k-contiguous bf16
// As/Bs: 2*4096 shorts each (16 KB each).
__device__ __forceinline__ void gemm_tile_g(
    const short* __restrict__ A, size_t ldA,
    const short* __restrict__ B, size_t ldB,
    int K, short* As, short* Bs, f32x4 acc[4][4])
{
    const int tid = threadIdx.x, lane = tid & 63, wid = tid >> 6;
    const int wr = (wid >> 1) * 64, wc = (wid & 1) * 64;
    const int fr = lane & 15, fk = (lane >> 4) * 8;
#pragma unroll
    for (int i = 0; i < 4; i++)
#pragma unroll
        for (int j = 0; j < 4; j++) acc[i][j] = (f32x4){0.f, 0.f, 0.f, 0.f};

    stage_tile(A, ldA, 0, As, wid, lane);
    stage_tile(B, ldB, 0, Bs, wid, lane);
    __syncthreads();                       // vmcnt(0) drain: buf0 ready
    const int nt = K >> 5;
    int cur = 0;
    for (int t = 0; t < nt; t++) {
        if (t + 1 < nt) {                  // issue next-tile stage into other buffer
            stage_tile(A, ldA, (t + 1) << 5, As + ((cur ^ 1) << 12), wid, lane);
            stage_tile(B, ldB, (t + 1) << 5, Bs + ((cur ^ 1) << 12), wid, lane);
        }
        const short* as = As + (cur << 12);
        const short* bs = Bs + (cur << 12);
        bf16x8 af[4], bfv[4];
#pragma unroll
        for (int i = 0; i < 4; i++) af[i] = *(const bf16x8*)&as[(wr + i * 16 + fr) * 32 + fk];
#pragma unroll
        for (int j = 0; j < 4; j++) bfv[j] = *(const bf16x8*)&bs[(wc + j * 16 + fr) * 32 + fk];
#pragma unroll
        for (int i = 0; i < 4; i++)
#pragma unroll
            for (int j = 0; j < 4; j++)
                acc[i][j] = __builtin_amdgcn_mfma_f32_16x16x32_bf16(af[i], bfv[j], acc[i][j], 0, 0, 0);
        __syncthreads();                   // drains stage (vmcnt) + protects buffer reuse
        cur ^= 1;
    }
}

// ---------------- prep: fused x->bf16, Wg/Wo transpose, head-W transpose, scales -----
__global__ __launch_bounds__(256) void prep(
    const float* __restrict__ x,
    const float* __restrict__ Wq, const float* __restrict__ Wk, const float* __restrict__ Wv,
    const float* __restrict__ Wg, const float* __restrict__ Wo,
    short* __restrict__ xb, short* __restrict__ WgT, short* __restrict__ WoT,
    short* __restrict__ Wt, float* __restrict__ sQ, float* __restrict__ sK)
{
    __shared__ float t[32][33];
    int bid = blockIdx.x;
    const int tid = threadIdx.x;
    if (bid < 4096) {                       // x -> bf16 flat
        const size_t i = ((size_t)bid * 256 + tid) * 8;
        float4 a = *(const float4*)&x[i];
        float4 b = *(const float4*)&x[i + 4];
        bf16x8 v;
        v[0] = f2bf(a.x); v[1] = f2bf(a.y); v[2] = f2bf(a.z); v[3] = f2bf(a.w);
        v[4] = f2bf(b.x); v[5] = f2bf(b.y); v[6] = f2bf(b.z); v[7] = f2bf(b.w);
        *(bf16x8*)&xb[i] = v;
        return;
    }
    bid -= 4096;
    if (bid < 2048) {                       // Wg / Wo 1024x1024 transpose -> bf16
        const float* __restrict__ S = (bid < 1024) ? Wg : Wo;
        short* __restrict__ D = (bid < 1024) ? WgT : WoT;
        const int tb = bid & 1023;
        const int bx = (tb & 31) * 32, by = (tb >> 5) * 32;
        const int xx = tid & 31, y0 = tid >> 5;
#pragma unroll
        for (int r = 0; r < 32; r += 8) t[y0 + r][xx] = S[(size_t)(by + y0 + r) * 1024 + bx + xx];
        __syncthreads();
#pragma unroll
        for (int r = 0; r < 32; r += 8) D[(size_t)(bx + y0 + r) * 1024 + by + xx] = f2bf(t[xx][y0 + r]);
        return;
    }
    bid -= 2048;
    if (bid < 384) {                        // 24 head matrices, 16 32x32 tiles each
        const int ht = bid >> 4, tb = bid & 15;
        const int typ = ht >> 3, h = ht & 7;
        const float* __restrict__ W = (typ == 0 ? Wq : (typ == 1 ? Wk : Wv)) + (size_t)h * HD * HD;
        short* __restrict__ D = Wt + (size_t)ht * HD * HD;
        const int bx = (tb & 3) * 32, by = (tb >> 2) * 32;
        const int xx = tid & 31, y0 = tid >> 5;
#pragma unroll
        for (int r = 0; r < 32; r += 8) t[y0 + r][xx] = W[(by + y0 + r) * HD + bx + xx];
        __syncthreads();
#pragma unroll
        for (int r = 0; r < 32; r += 8) D[(bx + y0 + r) * HD + by + xx] = f2bf(t[xx][y0 + r]);
        return;
    }
    bid -= 384;                             // 32 blocks: decay scale tables
    const int h = bid >> 2;
    const int s = (bid & 3) * 256 + tid;
    const double gamma = 1.0 - exp2((double)(-5 - h));
    const double lg = log2(gamma);
    sQ[h * SS + s] = (float)exp2(lg * (double)s);
    sK[h * SS + s] = (float)exp2(-lg * (double)s);
}

// ---------------- QKV: MFMA. Q'->bf16 [bh][s][d]; K'->bf16 [bh][d][t]; V->bf16 [bh][e][t]
__global__ __launch_bounds__(256) void g_qkv(
    const short* __restrict__ xb, const short* __restrict__ Wt,
    const float* __restrict__ sQ, const float* __restrict__ sK,
    short* __restrict__ Qb, short* __restrict__ Ktb, short* __restrict__ Vtb)
{
    __shared__ short As[2 * 4096], Bs[2 * 4096];
    f32x4 acc[4][4];
    const int m0 = blockIdx.x * 128;
    const int ht = blockIdx.y, typ = ht >> 3, h = ht & 7;
    gemm_tile_g(xb + (size_t)m0 * DD + h * HD, DD,
                Wt + (size_t)ht * HD * HD, HD, HD, As, Bs, acc);
    const int tid = threadIdx.x, lane = tid & 63, wid = tid >> 6;
    const int wr = (wid >> 1) * 64, wc = (wid & 1) * 64;
    const int r0 = (lane >> 4) * 4, c = lane & 15;
    const int b = m0 >> 10, s0 = m0 & (SS - 1);
    const int bh = (b << 3) + h;
    if (typ == 0) {
#pragma unroll
        for (int i = 0; i < 4; i++)
#pragma unroll
            for (int j = 0; j < 4; j++)
#pragma unroll
                for (int r = 0; r < 4; r++) {
                    const int s = s0 + wr + i * 16 + r0 + r;
                    Qb[((size_t)bh * SS + s) * HD + wc + j * 16 + c] =
                        f2bf(acc[i][j][r] * sQ[h * SS + s]);
                }
    } else if (typ == 1) {
        short* __restrict__ Ob = Ktb + (size_t)bh * HD * SS;
#pragma unroll
        for (int i = 0; i < 4; i++)
#pragma unroll
            for (int j = 0; j < 4; j++) {
                const int tb = s0 + wr + i * 16 + r0;
                const int d = wc + j * 16 + c;
                short4 o;
                o.x = f2bf(acc[i][j][0] * sK[h * SS + tb + 0]);
                o.y = f2bf(acc[i][j][1] * sK[h * SS + tb + 1]);
                o.z = f2bf(acc[i][j][2] * sK[h * SS + tb + 2]);
                o.w = f2bf(acc[i][j][3] * sK[h * SS + tb + 3]);
                *(short4*)&Ob[(size_t)d * SS + tb] = o;
            }
    } else {
        short* __restrict__ Ob = Vtb + (size_t)bh * HD * SS;
#pragma unroll
        for (int i = 0; i < 4; i++)
#pragma unroll
            for (int j = 0; j < 4; j++) {
                const int tb = s0 + wr + i * 16 + r0;
                const int e = wc + j * 16 + c;
                short4 o;
                o.x = f2bf(acc[i][j][0]); o.y = f2bf(acc[i][j][1]);
                o.z = f2bf(acc[i][j][2]); o.w = f2bf(acc[i][j][3]);
                *(short4*)&Ob[(size_t)e * SS + tb] = o;
            }
    }
}

// ---------------- KV: Mp[bid][e][d] = V_chunk^T K'_chunk (MFMA, split-4 over t) -----
__global__ __launch_bounds__(256) void g_kv(
    const short* __restrict__ Vtb, const short* __restrict__ Ktb, float* __restrict__ Mp)
{
    __shared__ short As[2 * 4096], Bs[2 * 4096];
    f32x4 acc[4][4];
    const int bid = blockIdx.x;
    const int chunk = bid & 3, bh = bid >> 2;
    gemm_tile_g(Vtb + (size_t)bh * HD * SS + chunk * 256, SS,
                Ktb + (size_t)bh * HD * SS + chunk * 256, SS, 256, As, Bs, acc);
    const int tid = threadIdx.x, lane = tid & 63, wid = tid >> 6;
    const int wr = (wid >> 1) * 64, wc = (wid & 1) * 64;
    const int r0 = (lane >> 4) * 4, c = lane & 15;
    float* __restrict__ Ob = Mp + (size_t)bid * HD * HD;
#pragma unroll
    for (int i = 0; i < 4; i++)
#pragma unroll
        for (int j = 0; j < 4; j++)
#pragma unroll
            for (int r = 0; r < 4; r++)
                Ob[(size_t)(wr + i * 16 + r0 + r) * HD + wc + j * 16 + c] = acc[i][j][r];
}

// ---------------- reduce 4 chunks + cvt: Mtb[bh][e][d] bf16 ----------------
__global__ __launch_bounds__(256) void g_mredcvt(const float* __restrict__ Mp, short* __restrict__ Mtb) {
    const size_t i = ((size_t)blockIdx.x * 256 + threadIdx.x) * 8;
    const size_t bh = i >> 14, ij = i & 16383;
    const float* p = Mp + (bh * 4) * 16384 + ij;
    float s[8];
#pragma unroll
    for (int q = 0; q < 8; q++) s[q] = 0.f;
#pragma unroll
    for (int cth = 0; cth < 4; cth++) {
        float4 a = *(const float4*)&p[cth * 16384];
        float4 b = *(const float4*)&p[cth * 16384 + 4];
        s[0] += a.x; s[1] += a.y; s[2] += a.z; s[3] += a.w;
        s[4] += b.x; s[5] += b.y; s[6] += b.z; s[7] += b.w;
    }
    bf16x8 v;
#pragma unroll
    for (int q = 0; q < 8; q++) v[q] = f2bf(s[q]);
    *(bf16x8*)&Mtb[i] = v;
}

// ---------------- QM: retb[bh][s][e] = Q' @ M (MFMA, bf16 out) ----------------
__global__ __launch_bounds__(256) void g_qm(
    const short* __restrict__ Qb, const short* __restrict__ Mtb, short* __restrict__ retb)
{
    __shared__ short As[2 * 4096], Bs[2 * 4096];
    f32x4 acc[4][4];
    const int bh = blockIdx.y, m0 = blockIdx.x * 128;
    gemm_tile_g(Qb + ((size_t)bh * SS + m0) * HD, HD,
                Mtb + (size_t)bh * HD * HD, HD, HD, As, Bs, acc);
    const int tid = threadIdx.x, lane = tid & 63, wid = tid >> 6;
    const int wr = (wid >> 1) * 64, wc = (wid & 1) * 64;
    const int r0 = (lane >> 4) * 4, c = lane & 15;
    short* __restrict__ O = retb + ((size_t)bh * SS + m0) * HD;
#pragma unroll
    for (int i = 0; i < 4; i++)
#pragma unroll
        for (int j = 0; j < 4; j++)
#pragma unroll
            for (int r = 0; r < 4; r++)
                O[(size_t)(wr + i * 16 + r0 + r) * HD + wc + j * 16 + c] = f2bf(acc[i][j][r]);
}

// ---------------- group stats (f64 accumulation) from bf16 ret ----------------
__global__ __launch_bounds__(256) void msr_stats(const short* __restrict__ retb, double* __restrict__ Sp)
{
    const int bid = blockIdx.x;
    const int chunk = bid & 7, bh = bid >> 3;
    const int tid = threadIdx.x;
    const int d = tid & 127, sp = tid >> 7;
    const short* __restrict__ base = retb + (size_t)bh * SS * HD;
    double sm = 0.0, sq = 0.0;
    const int send = chunk * 128 + 128;
    for (int s = chunk * 128 + sp; s < send; s += 2) {
        double v = (double)bf2f(base[(size_t)s * HD + d]);
        sm += v; sq += v * v;
    }
    __shared__ double Lsm[256];
    __shared__ double Lsq[256];
    Lsm[tid] = sm; Lsq[tid] = sq;
    __syncthreads();
    if (tid < 128) { Lsm[tid] += Lsm[tid + 128]; Lsq[tid] += Lsq[tid + 128]; }
    __syncthreads();
    if (tid < 16) {
        double a = 0.0, q = 0.0;
#pragma unroll
        for (int j = 0; j < 8; j++) { a += Lsm[tid * 8 + j]; q += Lsq[tid * 8 + j]; }
        const int b_ = bh >> 3, h_ = bh & 7;
        const int g = b_ * 128 + h_ * 16 + tid;
        Sp[(size_t)chunk * 2048 + g * 2 + 0] = a;
        Sp[(size_t)chunk * 2048 + g * 2 + 1] = q;
    }
}

__global__ __launch_bounds__(256) void msr_fstats(const double* __restrict__ Sp,
                                                  float* __restrict__ mean, float* __restrict__ rstd)
{
    const int g = blockIdx.x * 256 + threadIdx.x;
    if (g >= 1024) return;
    double sm = 0.0, sq = 0.0;
#pragma unroll
    for (int c = 0; c < 8; c++) { sm += Sp[(size_t)c * 2048 + g * 2]; sq += Sp[(size_t)c * 2048 + g * 2 + 1]; }
    const double mu = sm / 8192.0;
    double var = sq / 8192.0 - mu * mu;
    if (var < 0.0) var = 0.0;
    mean[g] = (float)mu;
    rstd[g] = (float)(1.0 / sqrt(var + (double)GN_EPS));
}

// ---------------- gate GEMM: gateb = ReLU(xb @ WgT^T) bf16 (MFMA) ----------------
__global__ __launch_bounds__(256) void g_gate(
    const short* __restrict__ xb, const short* __restrict__ WgT, short* __restrict__ gateb)
{
    __shared__ short As[2 * 4096], Bs[2 * 4096];
    f32x4 acc[4][4];
    const int n0 = blockIdx.x * 128, m0 = blockIdx.y * 128;
    gemm_tile_g(xb + (size_t)m0 * DD, DD, WgT + (size_t)n0 * DD, DD, DD, As, Bs, acc);
    const int tid = threadIdx.x, lane = tid & 63, wid = tid >> 6;
    const int wr = (wid >> 1) * 64, wc = (wid & 1) * 64;
    const int r0 = (lane >> 4) * 4, c = lane & 15;
#pragma unroll
    for (int i = 0; i < 4; i++)
#pragma unroll
        for (int j = 0; j < 4; j++)
#pragma unroll
            for (int r = 0; r < 4; r++)
                gateb[(size_t)(m0 + wr + i * 16 + r0 + r) * DD + n0 + wc + j * 16 + c] =
                    f2bf(fmaxf(acc[i][j][r], 0.f));
}

// ---------------- A-prep: Ab = gate ⊙ GN(ret) -> bf16 ----------------
__global__ __launch_bounds__(256) void aprep(
    const short* __restrict__ gateb, const short* __restrict__ retb,
    const float* __restrict__ mean, const float* __restrict__ rstd,
    const float* __restrict__ gng, const float* __restrict__ gnb, short* __restrict__ Ab)
{
    const size_t idx = ((size_t)blockIdx.x * 256 + threadIdx.x) * 4;
    const int m = (int)(idx >> 10), cc = (int)(idx & 1023);
    const int b_ = m >> 10, s = m & (SS - 1), h = cc >> 7, d = cc & 127, g = cc >> 3;
    short4 gv4 = *(const short4*)&gateb[idx];
    short4 rv4 = *(const short4*)&retb[((size_t)((b_ << 3) + h) * SS + s) * HD + d];
    const float mu = mean[b_ * 128 + g], rs = rstd[b_ * 128 + g];
    float4 gv = *(const float4*)&gng[cc];
    float4 bv = *(const float4*)&gnb[cc];
    short4 o;
    o.x = f2bf(bf2f(gv4.x) * ((bf2f(rv4.x) - mu) * rs * gv.x + bv.x));
    o.y = f2bf(bf2f(gv4.y) * ((bf2f(rv4.y) - mu) * rs * gv.y + bv.y));
    o.z = f2bf(bf2f(gv4.z) * ((bf2f(rv4.z) - mu) * rs * gv.z + bv.z));
    o.w = f2bf(bf2f(gv4.w) * ((bf2f(rv4.w) - mu) * rs * gv.w + bv.w));
    *(short4*)&Ab[idx] = o;
}

// ---------------- final GEMM: out = Ab @ WoT^T (MFMA, f32 out) ----------------
__global__ __launch_bounds__(256) void g_final(
    const short* __restrict__ Ab, const short* __restrict__ WoT, float* __restrict__ out)
{
    __shared__ short As[2 * 4096], Bs[2 * 4096];
    f32x4 acc[4][4];
    const int n0 = blockIdx.x * 128, m0 = blockIdx.y * 128;
    gemm_tile_g(Ab + (size_t)m0 * DD, DD, WoT + (size_t)n0 * DD, DD, DD, As, Bs, acc);
    const int tid = threadIdx.x, lane = tid & 63, wid = tid >> 6;
    const int wr = (wid >> 1) * 64, wc = (wid & 1) * 64;
    const int r0 = (lane >> 4) * 4, c = lane & 15;
#pragma unroll
    for (int i = 0; i < 4; i++)
#pragma unroll
        for (int j = 0; j < 4; j++)
#pragma unroll
            for (int r = 0; r < 4; r++)
                out[(size_t)(m0 + wr + i * 16 + r0 + r) * DD + n0 + wc + j * 16 + c] = acc[i][j][r];
}

extern "C" void kernel_launch(void* const* d_in, const int* in_sizes, int n_in,
                              void* d_out, int out_size, void* d_ws, size_t ws_size,
                              hipStream_t stream)
{
    const float* x   = (const float*)d_in[0];
    const float* Wq  = (const float*)d_in[1];
    const float* Wk  = (const float*)d_in[2];
    const float* Wv  = (const float*)d_in[3];
    const float* Wg  = (const float*)d_in[4];
    const float* Wo  = (const float*)d_in[5];
    const float* gng = (const float*)d_in[6];
    const float* gnb = (const float*)d_in[7];
    float* out = (float*)d_out;

    char* ws = (char*)d_ws;
    size_t off = 0;
    auto alloc = [&](size_t bytes) -> void* {
        void* p = ws + off;
        off += (bytes + 255) & ~(size_t)255;
        return p;
    };
    const size_t NE = (size_t)BB * SS * DD;   // 8,388,608
    float*  sQ    = (float*)alloc((size_t)HH * SS * sizeof(float));
    float*  sK    = (float*)alloc((size_t)HH * SS * sizeof(float));
    short*  xb    = (short*)alloc(NE * sizeof(short));
    short*  WgT   = (short*)alloc((size_t)DD * DD * sizeof(short));
    short*  WoT   = (short*)alloc((size_t)DD * DD * sizeof(short));
    short*  Wt    = (short*)alloc((size_t)24 * HD * HD * sizeof(short));
    short*  Qb    = (short*)alloc(NE * sizeof(short));
    short*  Ktb   = (short*)alloc(NE * sizeof(short));
    short*  Vtb   = (short*)alloc(NE * sizeof(short));
    short*  retb  = (short*)alloc(NE * sizeof(short));
    short*  gateb = (short*)alloc(NE * sizeof(short));
    short*  Ab    = (short*)alloc(NE * sizeof(short));
    float*  Mp    = (float*)alloc((size_t)256 * HD * HD * sizeof(float));
    short*  Mtb   = (short*)alloc((size_t)64 * HD * HD * sizeof(short));
    double* Sp    = (double*)alloc((size_t)8 * 1024 * 2 * sizeof(double));
    float*  meanw = (float*)alloc(1024 * sizeof(float));
    float*  rstdw = (float*)alloc(1024 * sizeof(float));

    prep<<<dim3(6560), 256, 0, stream>>>(x, Wq, Wk, Wv, Wg, Wo, xb, WgT, WoT, Wt, sQ, sK);
    g_qkv<<<dim3(64, 24), 256, 0, stream>>>(xb, Wt, sQ, sK, Qb, Ktb, Vtb);
    g_kv<<<dim3(256), 256, 0, stream>>>(Vtb, Ktb, Mp);
    g_mredcvt<<<dim3(512), 256, 0, stream>>>(Mp, Mtb);
    g_qm<<<dim3(8, 64), 256, 0, stream>>>(Qb, Mtb, retb);
    msr_stats<<<dim3(512), 256, 0, stream>>>(retb, Sp);
    msr_fstats<<<dim3(4), 256, 0, stream>>>(Sp, meanw, rstdw);
    g_gate<<<dim3(8, 64), 256, 0, stream>>>(xb, WgT, gateb);
    aprep<<<dim3(8192), 256, 0, stream>>>(gateb, retb, meanw, rstdw, gng, gnb, Ab);
    g_final<<<dim3(8, 64), 256, 0, stream>>>(Ab, WoT, out);
}

// Round 7
// 141.362 us; speedup vs baseline: 4.8664x; 1.1658x over previous
//
#include <hip/hip_runtime.h>

#define BB 8
#define SS 1024
#define DD 1024
#define HH 8
#define HD 128
#define GN_EPS 1e-3f

typedef __attribute__((ext_vector_type(8))) short bf16x8;
typedef __attribute__((ext_vector_type(4))) float f32x4;

__device__ __forceinline__ short f2bf(float f) {
    unsigned u = __float_as_uint(f);
    return (short)((u + 0x7fffu + ((u >> 16) & 1u)) >> 16);
}
__device__ __forceinline__ float bf2f(short s) {
    return __uint_as_float(((unsigned)(unsigned short)s) << 16);
}

__device__ __forceinline__ void gload16(const void* g, void* l) {
    __builtin_amdgcn_global_load_lds((const __attribute__((address_space(1))) void*)g,
                                     (__attribute__((address_space(3))) void*)l, 16, 0, 0);
}

// ---- stage one 128x32-short tile (8 KB) via global_load_lds, linear row-major LDS ----
__device__ __forceinline__ void stage_tile(const short* __restrict__ G, size_t ld, int k0,
                                           short* lds, int wid, int lane) {
#pragma unroll
    for (int i = 0; i < 2; i++) {
        const int seg = wid * 2 + i;
        const int row = seg * 16 + (lane >> 2);
        gload16(G + (size_t)row * ld + k0 + (lane & 3) * 8, lds + seg * 512);
    }
}

// ---------------- 128x128xK MFMA tile core: global_load_lds + LDS double-buffer ------
__device__ __forceinline__ void gemm_tile_g(
    const short* __restrict__ A, size_t ldA,
    const short* __restrict__ B, size_t ldB,
    int K, short* As, short* Bs, f32x4 acc[4][4])
{
    const int tid = threadIdx.x, lane = tid & 63, wid = tid >> 6;
    const int wr = (wid >> 1) * 64, wc = (wid & 1) * 64;
    const int fr = lane & 15, fk = (lane >> 4) * 8;
#pragma unroll
    for (int i = 0; i < 4; i++)
#pragma unroll
        for (int j = 0; j < 4; j++) acc[i][j] = (f32x4){0.f, 0.f, 0.f, 0.f};

    stage_tile(A, ldA, 0, As, wid, lane);
    stage_tile(B, ldB, 0, Bs, wid, lane);
    __syncthreads();
    const int nt = K >> 5;
    int cur = 0;
    for (int t = 0; t < nt; t++) {
        if (t + 1 < nt) {
            stage_tile(A, ldA, (t + 1) << 5, As + ((cur ^ 1) << 12), wid, lane);
            stage_tile(B, ldB, (t + 1) << 5, Bs + ((cur ^ 1) << 12), wid, lane);
        }
        const short* as = As + (cur << 12);
        const short* bs = Bs + (cur << 12);
        bf16x8 af[4], bfv[4];
#pragma unroll
        for (int i = 0; i < 4; i++) af[i] = *(const bf16x8*)&as[(wr + i * 16 + fr) * 32 + fk];
#pragma unroll
        for (int j = 0; j < 4; j++) bfv[j] = *(const bf16x8*)&bs[(wc + j * 16 + fr) * 32 + fk];
#pragma unroll
        for (int i = 0; i < 4; i++)
#pragma unroll
            for (int j = 0; j < 4; j++)
                acc[i][j] = __builtin_amdgcn_mfma_f32_16x16x32_bf16(af[i], bfv[j], acc[i][j], 0, 0, 0);
        __syncthreads();
        cur ^= 1;
    }
}

// ---------------- prep: x->bf16, W transposes, scales, zero Sp ----------------
__global__ __launch_bounds__(256) void prep(
    const float* __restrict__ x,
    const float* __restrict__ Wq, const float* __restrict__ Wk, const float* __restrict__ Wv,
    const float* __restrict__ Wg, const float* __restrict__ Wo,
    short* __restrict__ xb, short* __restrict__ WgT, short* __restrict__ WoT,
    short* __restrict__ Wt, float* __restrict__ sQ, float* __restrict__ sK,
    float* __restrict__ Sp)
{
    __shared__ float t[32][33];
    int bid = blockIdx.x;
    const int tid = threadIdx.x;
    if (bid < 4096) {                       // x -> bf16 flat
        const size_t i = ((size_t)bid * 256 + tid) * 8;
        float4 a = *(const float4*)&x[i];
        float4 b = *(const float4*)&x[i + 4];
        bf16x8 v;
        v[0] = f2bf(a.x); v[1] = f2bf(a.y); v[2] = f2bf(a.z); v[3] = f2bf(a.w);
        v[4] = f2bf(b.x); v[5] = f2bf(b.y); v[6] = f2bf(b.z); v[7] = f2bf(b.w);
        *(bf16x8*)&xb[i] = v;
        return;
    }
    bid -= 4096;
    if (bid < 2048) {                       // Wg / Wo transpose -> bf16
        const float* __restrict__ S = (bid < 1024) ? Wg : Wo;
        short* __restrict__ D = (bid < 1024) ? WgT : WoT;
        const int tb = bid & 1023;
        const int bx = (tb & 31) * 32, by = (tb >> 5) * 32;
        const int xx = tid & 31, y0 = tid >> 5;
#pragma unroll
        for (int r = 0; r < 32; r += 8) t[y0 + r][xx] = S[(size_t)(by + y0 + r) * 1024 + bx + xx];
        __syncthreads();
#pragma unroll
        for (int r = 0; r < 32; r += 8) D[(size_t)(bx + y0 + r) * 1024 + by + xx] = f2bf(t[xx][y0 + r]);
        return;
    }
    bid -= 2048;
    if (bid < 384) {                        // 24 head matrices
        const int ht = bid >> 4, tb = bid & 15;
        const int typ = ht >> 3, h = ht & 7;
        const float* __restrict__ W = (typ == 0 ? Wq : (typ == 1 ? Wk : Wv)) + (size_t)h * HD * HD;
        short* __restrict__ D = Wt + (size_t)ht * HD * HD;
        const int bx = (tb & 3) * 32, by = (tb >> 2) * 32;
        const int xx = tid & 31, y0 = tid >> 5;
#pragma unroll
        for (int r = 0; r < 32; r += 8) t[y0 + r][xx] = W[(by + y0 + r) * HD + bx + xx];
        __syncthreads();
#pragma unroll
        for (int r = 0; r < 32; r += 8) D[(bx + y0 + r) * HD + by + xx] = f2bf(t[xx][y0 + r]);
        return;
    }
    bid -= 384;
    if (bid < 32) {                         // decay scale tables
        const int h = bid >> 2;
        const int s = (bid & 3) * 256 + tid;
        const double gamma = 1.0 - exp2((double)(-5 - h));
        const double lg = log2(gamma);
        sQ[h * SS + s] = (float)exp2(lg * (double)s);
        sK[h * SS + s] = (float)exp2(-lg * (double)s);
        return;
    }
    // last block: zero Sp[2048]
    *(float4*)&Sp[tid * 8] = (float4){0.f, 0.f, 0.f, 0.f};
    *(float4*)&Sp[tid * 8 + 4] = (float4){0.f, 0.f, 0.f, 0.f};
}

// ---------------- QKV: MFMA. Q'->bf16 [bh][s][d]; K'->bf16 [bh][d][t]; V->bf16 [bh][e][t]
__global__ __launch_bounds__(256) void g_qkv(
    const short* __restrict__ xb, const short* __restrict__ Wt,
    const float* __restrict__ sQ, const float* __restrict__ sK,
    short* __restrict__ Qb, short* __restrict__ Ktb, short* __restrict__ Vtb)
{
    __shared__ short As[2 * 4096], Bs[2 * 4096];
    f32x4 acc[4][4];
    const int m0 = blockIdx.x * 128;
    const int ht = blockIdx.y, typ = ht >> 3, h = ht & 7;
    gemm_tile_g(xb + (size_t)m0 * DD + h * HD, DD,
                Wt + (size_t)ht * HD * HD, HD, HD, As, Bs, acc);
    const int tid = threadIdx.x, lane = tid & 63, wid = tid >> 6;
    const int wr = (wid >> 1) * 64, wc = (wid & 1) * 64;
    const int r0 = (lane >> 4) * 4, c = lane & 15;
    const int b = m0 >> 10, s0 = m0 & (SS - 1);
    const int bh = (b << 3) + h;
    if (typ == 0) {
#pragma unroll
        for (int i = 0; i < 4; i++)
#pragma unroll
            for (int j = 0; j < 4; j++)
#pragma unroll
                for (int r = 0; r < 4; r++) {
                    const int s = s0 + wr + i * 16 + r0 + r;
                    Qb[((size_t)bh * SS + s) * HD + wc + j * 16 + c] =
                        f2bf(acc[i][j][r] * sQ[h * SS + s]);
                }
    } else if (typ == 1) {
        short* __restrict__ Ob = Ktb + (size_t)bh * HD * SS;
#pragma unroll
        for (int i = 0; i < 4; i++)
#pragma unroll
            for (int j = 0; j < 4; j++) {
                const int tb = s0 + wr + i * 16 + r0;
                const int d = wc + j * 16 + c;
                short4 o;
                o.x = f2bf(acc[i][j][0] * sK[h * SS + tb + 0]);
                o.y = f2bf(acc[i][j][1] * sK[h * SS + tb + 1]);
                o.z = f2bf(acc[i][j][2] * sK[h * SS + tb + 2]);
                o.w = f2bf(acc[i][j][3] * sK[h * SS + tb + 3]);
                *(short4*)&Ob[(size_t)d * SS + tb] = o;
            }
    } else {
        short* __restrict__ Ob = Vtb + (size_t)bh * HD * SS;
#pragma unroll
        for (int i = 0; i < 4; i++)
#pragma unroll
            for (int j = 0; j < 4; j++) {
                const int tb = s0 + wr + i * 16 + r0;
                const int e = wc + j * 16 + c;
                short4 o;
                o.x = f2bf(acc[i][j][0]); o.y = f2bf(acc[i][j][1]);
                o.z = f2bf(acc[i][j][2]); o.w = f2bf(acc[i][j][3]);
                *(short4*)&Ob[(size_t)e * SS + tb] = o;
            }
    }
}

// ---------------- KV: Mp[bid][e][d] = V_chunk^T K'_chunk (MFMA, split-4 over t) -----
__global__ __launch_bounds__(256) void g_kv(
    const short* __restrict__ Vtb, const short* __restrict__ Ktb, float* __restrict__ Mp)
{
    __shared__ short As[2 * 4096], Bs[2 * 4096];
    f32x4 acc[4][4];
    const int bid = blockIdx.x;
    const int chunk = bid & 3, bh = bid >> 2;
    gemm_tile_g(Vtb + (size_t)bh * HD * SS + chunk * 256, SS,
                Ktb + (size_t)bh * HD * SS + chunk * 256, SS, 256, As, Bs, acc);
    const int tid = threadIdx.x, lane = tid & 63, wid = tid >> 6;
    const int wr = (wid >> 1) * 64, wc = (wid & 1) * 64;
    const int r0 = (lane >> 4) * 4, c = lane & 15;
    float* __restrict__ Ob = Mp + (size_t)bid * HD * HD;
#pragma unroll
    for (int i = 0; i < 4; i++)
#pragma unroll
        for (int j = 0; j < 4; j++)
#pragma unroll
            for (int r = 0; r < 4; r++)
                Ob[(size_t)(wr + i * 16 + r0 + r) * HD + wc + j * 16 + c] = acc[i][j][r];
}

// ---------------- reduce 4 chunks + cvt: Mtb[bh][e][d] bf16 ----------------
__global__ __launch_bounds__(256) void g_mredcvt(const float* __restrict__ Mp, short* __restrict__ Mtb) {
    const size_t i = ((size_t)blockIdx.x * 256 + threadIdx.x) * 8;
    const size_t bh = i >> 14, ij = i & 16383;
    const float* p = Mp + (bh * 4) * 16384 + ij;
    float s[8];
#pragma unroll
    for (int q = 0; q < 8; q++) s[q] = 0.f;
#pragma unroll
    for (int cth = 0; cth < 4; cth++) {
        float4 a = *(const float4*)&p[cth * 16384];
        float4 b = *(const float4*)&p[cth * 16384 + 4];
        s[0] += a.x; s[1] += a.y; s[2] += a.z; s[3] += a.w;
        s[4] += b.x; s[5] += b.y; s[6] += b.z; s[7] += b.w;
    }
    bf16x8 v;
#pragma unroll
    for (int q = 0; q < 8; q++) v[q] = f2bf(s[q]);
    *(bf16x8*)&Mtb[i] = v;
}

// ---------------- QM: retb = Q' @ M (MFMA, bf16 out) + fused group-stat atomics -----
__global__ __launch_bounds__(256) void g_qm(
    const short* __restrict__ Qb, const short* __restrict__ Mtb,
    short* __restrict__ retb, float* __restrict__ Sp)
{
    __shared__ short As[2 * 4096], Bs[2 * 4096];
    f32x4 acc[4][4];
    const int bh = blockIdx.y, m0 = blockIdx.x * 128;
    gemm_tile_g(Qb + ((size_t)bh * SS + m0) * HD, HD,
                Mtb + (size_t)bh * HD * HD, HD, HD, As, Bs, acc);
    const int tid = threadIdx.x, lane = tid & 63, wid = tid >> 6;
    const int wr = (wid >> 1) * 64, wc = (wid & 1) * 64;
    const int r0 = (lane >> 4) * 4, c = lane & 15;
    short* __restrict__ O = retb + ((size_t)bh * SS + m0) * HD;
#pragma unroll
    for (int i = 0; i < 4; i++)
#pragma unroll
        for (int j = 0; j < 4; j++)
#pragma unroll
            for (int r = 0; r < 4; r++)
                O[(size_t)(wr + i * 16 + r0 + r) * HD + wc + j * 16 + c] = f2bf(acc[i][j][r]);

    // fused group stats: per-thread partials over (i,r) for each j, wave-reduce, atomic.
    // Wave tile: row = wr + i*16 + (lane>>4)*4 + r, col = wc + j*16 + (lane&15).
    // Reduce over lane bits {0,1,2} (cols within group-of-8) and {4,5} (row groups):
    // masks {1,2,4,16,32}. Lane bit 3 selects the column-group half (hi).
    float psm[4], psq[4];
#pragma unroll
    for (int j = 0; j < 4; j++) { psm[j] = 0.f; psq[j] = 0.f; }
#pragma unroll
    for (int i = 0; i < 4; i++)
#pragma unroll
        for (int j = 0; j < 4; j++)
#pragma unroll
            for (int r = 0; r < 4; r++) {
                const float v = acc[i][j][r];
                psm[j] += v; psq[j] += v * v;
            }
    const int masks[5] = {1, 2, 4, 16, 32};
#pragma unroll
    for (int mk = 0; mk < 5; mk++) {
#pragma unroll
        for (int j = 0; j < 4; j++) {
            psm[j] += __shfl_xor(psm[j], masks[mk], 64);
            psq[j] += __shfl_xor(psq[j], masks[mk], 64);
        }
    }
    if ((lane & 7) == 0 && lane < 16) {      // lanes 0 (hi=0) and 8 (hi=1)
        const int hi = lane >> 3;
        const int b_ = bh >> 3, h_ = bh & 7;
#pragma unroll
        for (int j = 0; j < 4; j++) {
            const int g = b_ * 128 + h_ * 16 + (wid & 1) * 8 + j * 2 + hi;
            atomicAdd(&Sp[g * 2 + 0], psm[j]);
            atomicAdd(&Sp[g * 2 + 1], psq[j]);
        }
    }
}

// ---------------- gate GEMM + fused GN×gate epilogue: Ab = relu(x@Wg) ⊙ GN(ret) -----
__global__ __launch_bounds__(256) void g_gate(
    const short* __restrict__ xb, const short* __restrict__ WgT,
    const short* __restrict__ retb, const float* __restrict__ Sp,
    const float* __restrict__ gng, const float* __restrict__ gnb,
    short* __restrict__ Ab)
{
    __shared__ short As[2 * 4096], Bs[2 * 4096];
    f32x4 acc[4][4];
    const int n0 = blockIdx.x * 128, m0 = blockIdx.y * 128;
    gemm_tile_g(xb + (size_t)m0 * DD, DD, WgT + (size_t)n0 * DD, DD, DD, As, Bs, acc);
    const int tid = threadIdx.x, lane = tid & 63, wid = tid >> 6;
    const int wr = (wid >> 1) * 64, wc = (wid & 1) * 64;
    const int r0 = (lane >> 4) * 4, c = lane & 15;
    const int b_ = m0 >> 10, s0 = m0 & (SS - 1);
#pragma unroll
    for (int j = 0; j < 4; j++) {
        const int n = n0 + wc + j * 16 + c;
        const int g = b_ * 128 + (n >> 3);
        const float sm = Sp[g * 2 + 0], sq = Sp[g * 2 + 1];
        const float mu = sm * (1.0f / 8192.0f);
        float var = sq * (1.0f / 8192.0f) - mu * mu;
        if (var < 0.f) var = 0.f;
        const float rs = rsqrtf(var + GN_EPS);
        const float gam = gng[n], bet = gnb[n];
        const int h = n >> 7, d = n & 127;
        const short* __restrict__ rbase = retb + ((size_t)((b_ << 3) + h) * SS) * HD + d;
#pragma unroll
        for (int i = 0; i < 4; i++)
#pragma unroll
            for (int r = 0; r < 4; r++) {
                const int s = s0 + wr + i * 16 + r0 + r;
                const float rv = bf2f(rbase[(size_t)s * HD]);
                const float y = (rv - mu) * rs * gam + bet;
                const float gate = fmaxf(acc[i][j][r], 0.f);
                Ab[(size_t)(m0 + wr + i * 16 + r0 + r) * DD + n] = f2bf(gate * y);
            }
    }
}

// ---------------- final GEMM: out = Ab @ WoT^T (MFMA, f32 out) ----------------
__global__ __launch_bounds__(256) void g_final(
    const short* __restrict__ Ab, const short* __restrict__ WoT, float* __restrict__ out)
{
    __shared__ short As[2 * 4096], Bs[2 * 4096];
    f32x4 acc[4][4];
    const int n0 = blockIdx.x * 128, m0 = blockIdx.y * 128;
    gemm_tile_g(Ab + (size_t)m0 * DD, DD, WoT + (size_t)n0 * DD, DD, DD, As, Bs, acc);
    const int tid = threadIdx.x, lane = tid & 63, wid = tid >> 6;
    const int wr = (wid >> 1) * 64, wc = (wid & 1) * 64;
    const int r0 = (lane >> 4) * 4, c = lane & 15;
#pragma unroll
    for (int i = 0; i < 4; i++)
#pragma unroll
        for (int j = 0; j < 4; j++)
#pragma unroll
            for (int r = 0; r < 4; r++)
                out[(size_t)(m0 + wr + i * 16 + r0 + r) * DD + n0 + wc + j * 16 + c] = acc[i][j][r];
}

extern "C" void kernel_launch(void* const* d_in, const int* in_sizes, int n_in,
                              void* d_out, int out_size, void* d_ws, size_t ws_size,
                              hipStream_t stream)
{
    const float* x   = (const float*)d_in[0];
    const float* Wq  = (const float*)d_in[1];
    const float* Wk  = (const float*)d_in[2];
    const float* Wv  = (const float*)d_in[3];
    const float* Wg  = (const float*)d_in[4];
    const float* Wo  = (const float*)d_in[5];
    const float* gng = (const float*)d_in[6];
    const float* gnb = (const float*)d_in[7];
    float* out = (float*)d_out;

    char* ws = (char*)d_ws;
    size_t off = 0;
    auto alloc = [&](size_t bytes) -> void* {
        void* p = ws + off;
        off += (bytes + 255) & ~(size_t)255;
        return p;
    };
    const size_t NE = (size_t)BB * SS * DD;   // 8,388,608
    float*  sQ    = (float*)alloc((size_t)HH * SS * sizeof(float));
    float*  sK    = (float*)alloc((size_t)HH * SS * sizeof(float));
    short*  xb    = (short*)alloc(NE * sizeof(short));
    short*  WgT   = (short*)alloc((size_t)DD * DD * sizeof(short));
    short*  WoT   = (short*)alloc((size_t)DD * DD * sizeof(short));
    short*  Wt    = (short*)alloc((size_t)24 * HD * HD * sizeof(short));
    short*  Qb    = (short*)alloc(NE * sizeof(short));
    short*  Ktb   = (short*)alloc(NE * sizeof(short));
    short*  Vtb   = (short*)alloc(NE * sizeof(short));
    short*  retb  = (short*)alloc(NE * sizeof(short));
    short*  Ab    = (short*)alloc(NE * sizeof(short));
    float*  Mp    = (float*)alloc((size_t)256 * HD * HD * sizeof(float));
    short*  Mtb   = (short*)alloc((size_t)64 * HD * HD * sizeof(short));
    float*  Sp    = (float*)alloc((size_t)1024 * 2 * sizeof(float));

    prep<<<dim3(6561), 256, 0, stream>>>(x, Wq, Wk, Wv, Wg, Wo, xb, WgT, WoT, Wt, sQ, sK, Sp);
    g_qkv<<<dim3(64, 24), 256, 0, stream>>>(xb, Wt, sQ, sK, Qb, Ktb, Vtb);
    g_kv<<<dim3(256), 256, 0, stream>>>(Vtb, Ktb, Mp);
    g_mredcvt<<<dim3(512), 256, 0, stream>>>(Mp, Mtb);
    g_qm<<<dim3(8, 64), 256, 0, stream>>>(Qb, Mtb, retb, Sp);
    g_gate<<<dim3(8, 64), 256, 0, stream>>>(xb, WgT, retb, Sp, gng, gnb, Ab);
    g_final<<<dim3(8, 64), 256, 0, stream>>>(Ab, WoT, out);
}

// Round 8
// 141.194 us; speedup vs baseline: 4.8722x; 1.0012x over previous
//
#include <hip/hip_runtime.h>

#define BB 8
#define SS 1024
#define DD 1024
#define HH 8
#define HD 128
#define GN_EPS 1e-3f

typedef __attribute__((ext_vector_type(8))) short bf16x8;
typedef __attribute__((ext_vector_type(4))) float f32x4;

__device__ __forceinline__ short f2bf(float f) {
    unsigned u = __float_as_uint(f);
    return (short)((u + 0x7fffu + ((u >> 16) & 1u)) >> 16);
}
__device__ __forceinline__ float bf2f(short s) {
    return __uint_as_float(((unsigned)(unsigned short)s) << 16);
}

__device__ __forceinline__ void gload16(const void* g, void* l) {
    __builtin_amdgcn_global_load_lds((const __attribute__((address_space(1))) void*)g,
                                     (__attribute__((address_space(3))) void*)l, 16, 0, 0);
}

// ---- stage one 128x32-short tile (8 KB) via global_load_lds, linear row-major LDS ----
__device__ __forceinline__ void stage_tile(const short* __restrict__ G, size_t ld, int k0,
                                           short* lds, int wid, int lane) {
#pragma unroll
    for (int i = 0; i < 2; i++) {
        const int seg = wid * 2 + i;
        const int row = seg * 16 + (lane >> 2);
        gload16(G + (size_t)row * ld + k0 + (lane & 3) * 8, lds + seg * 512);
    }
}

// ---------------- 128x128xK MFMA tile core: global_load_lds + LDS double-buffer ------
__device__ __forceinline__ void gemm_tile_g(
    const short* __restrict__ A, size_t ldA,
    const short* __restrict__ B, size_t ldB,
    int K, short* As, short* Bs, f32x4 acc[4][4])
{
    const int tid = threadIdx.x, lane = tid & 63, wid = tid >> 6;
    const int wr = (wid >> 1) * 64, wc = (wid & 1) * 64;
    const int fr = lane & 15, fk = (lane >> 4) * 8;
#pragma unroll
    for (int i = 0; i < 4; i++)
#pragma unroll
        for (int j = 0; j < 4; j++) acc[i][j] = (f32x4){0.f, 0.f, 0.f, 0.f};

    stage_tile(A, ldA, 0, As, wid, lane);
    stage_tile(B, ldB, 0, Bs, wid, lane);
    __syncthreads();
    const int nt = K >> 5;
    int cur = 0;
    for (int t = 0; t < nt; t++) {
        if (t + 1 < nt) {
            stage_tile(A, ldA, (t + 1) << 5, As + ((cur ^ 1) << 12), wid, lane);
            stage_tile(B, ldB, (t + 1) << 5, Bs + ((cur ^ 1) << 12), wid, lane);
        }
        const short* as = As + (cur << 12);
        const short* bs = Bs + (cur << 12);
        bf16x8 af[4], bfv[4];
#pragma unroll
        for (int i = 0; i < 4; i++) af[i] = *(const bf16x8*)&as[(wr + i * 16 + fr) * 32 + fk];
#pragma unroll
        for (int j = 0; j < 4; j++) bfv[j] = *(const bf16x8*)&bs[(wc + j * 16 + fr) * 32 + fk];
#pragma unroll
        for (int i = 0; i < 4; i++)
#pragma unroll
            for (int j = 0; j < 4; j++)
                acc[i][j] = __builtin_amdgcn_mfma_f32_16x16x32_bf16(af[i], bfv[j], acc[i][j], 0, 0, 0);
        __syncthreads();
        cur ^= 1;
    }
}

// ---------------- prep: x->bf16, W transposes, scales, zero Sp ----------------
__global__ __launch_bounds__(256) void prep(
    const float* __restrict__ x,
    const float* __restrict__ Wq, const float* __restrict__ Wk, const float* __restrict__ Wv,
    const float* __restrict__ Wg, const float* __restrict__ Wo,
    short* __restrict__ xb, short* __restrict__ WgT, short* __restrict__ WoT,
    short* __restrict__ Wt, float* __restrict__ sQ, float* __restrict__ sK,
    float* __restrict__ Sp)
{
    __shared__ float t[32][33];
    int bid = blockIdx.x;
    const int tid = threadIdx.x;
    if (bid < 4096) {                       // x -> bf16 flat
        const size_t i = ((size_t)bid * 256 + tid) * 8;
        float4 a = *(const float4*)&x[i];
        float4 b = *(const float4*)&x[i + 4];
        bf16x8 v;
        v[0] = f2bf(a.x); v[1] = f2bf(a.y); v[2] = f2bf(a.z); v[3] = f2bf(a.w);
        v[4] = f2bf(b.x); v[5] = f2bf(b.y); v[6] = f2bf(b.z); v[7] = f2bf(b.w);
        *(bf16x8*)&xb[i] = v;
        return;
    }
    bid -= 4096;
    if (bid < 2048) {                       // Wg / Wo transpose -> bf16
        const float* __restrict__ S = (bid < 1024) ? Wg : Wo;
        short* __restrict__ D = (bid < 1024) ? WgT : WoT;
        const int tb = bid & 1023;
        const int bx = (tb & 31) * 32, by = (tb >> 5) * 32;
        const int xx = tid & 31, y0 = tid >> 5;
#pragma unroll
        for (int r = 0; r < 32; r += 8) t[y0 + r][xx] = S[(size_t)(by + y0 + r) * 1024 + bx + xx];
        __syncthreads();
#pragma unroll
        for (int r = 0; r < 32; r += 8) D[(size_t)(bx + y0 + r) * 1024 + by + xx] = f2bf(t[xx][y0 + r]);
        return;
    }
    bid -= 2048;
    if (bid < 384) {                        // 24 head matrices
        const int ht = bid >> 4, tb = bid & 15;
        const int typ = ht >> 3, h = ht & 7;
        const float* __restrict__ W = (typ == 0 ? Wq : (typ == 1 ? Wk : Wv)) + (size_t)h * HD * HD;
        short* __restrict__ D = Wt + (size_t)ht * HD * HD;
        const int bx = (tb & 3) * 32, by = (tb >> 2) * 32;
        const int xx = tid & 31, y0 = tid >> 5;
#pragma unroll
        for (int r = 0; r < 32; r += 8) t[y0 + r][xx] = W[(by + y0 + r) * HD + bx + xx];
        __syncthreads();
#pragma unroll
        for (int r = 0; r < 32; r += 8) D[(bx + y0 + r) * HD + by + xx] = f2bf(t[xx][y0 + r]);
        return;
    }
    bid -= 384;
    if (bid < 32) {                         // decay scale tables
        const int h = bid >> 2;
        const int s = (bid & 3) * 256 + tid;
        const double gamma = 1.0 - exp2((double)(-5 - h));
        const double lg = log2(gamma);
        sQ[h * SS + s] = (float)exp2(lg * (double)s);
        sK[h * SS + s] = (float)exp2(-lg * (double)s);
        return;
    }
    // last block: zero Sp[2048]
    *(float4*)&Sp[tid * 8] = (float4){0.f, 0.f, 0.f, 0.f};
    *(float4*)&Sp[tid * 8 + 4] = (float4){0.f, 0.f, 0.f, 0.f};
}

// ---------------- QKV: MFMA. Q'->bf16 [bh][s][d]; K'->bf16 [bh][d][t]; V->bf16 [bh][e][t]
__global__ __launch_bounds__(256) void g_qkv(
    const short* __restrict__ xb, const short* __restrict__ Wt,
    const float* __restrict__ sQ, const float* __restrict__ sK,
    short* __restrict__ Qb, short* __restrict__ Ktb, short* __restrict__ Vtb)
{
    __shared__ short As[2 * 4096], Bs[2 * 4096];
    f32x4 acc[4][4];
    const int m0 = blockIdx.x * 128;
    const int ht = blockIdx.y, typ = ht >> 3, h = ht & 7;
    gemm_tile_g(xb + (size_t)m0 * DD + h * HD, DD,
                Wt + (size_t)ht * HD * HD, HD, HD, As, Bs, acc);
    const int tid = threadIdx.x, lane = tid & 63, wid = tid >> 6;
    const int wr = (wid >> 1) * 64, wc = (wid & 1) * 64;
    const int r0 = (lane >> 4) * 4, c = lane & 15;
    const int b = m0 >> 10, s0 = m0 & (SS - 1);
    const int bh = (b << 3) + h;
    if (typ == 0) {
#pragma unroll
        for (int i = 0; i < 4; i++)
#pragma unroll
            for (int j = 0; j < 4; j++)
#pragma unroll
                for (int r = 0; r < 4; r++) {
                    const int s = s0 + wr + i * 16 + r0 + r;
                    Qb[((size_t)bh * SS + s) * HD + wc + j * 16 + c] =
                        f2bf(acc[i][j][r] * sQ[h * SS + s]);
                }
    } else if (typ == 1) {
        short* __restrict__ Ob = Ktb + (size_t)bh * HD * SS;
#pragma unroll
        for (int i = 0; i < 4; i++)
#pragma unroll
            for (int j = 0; j < 4; j++) {
                const int tb = s0 + wr + i * 16 + r0;
                const int d = wc + j * 16 + c;
                short4 o;
                o.x = f2bf(acc[i][j][0] * sK[h * SS + tb + 0]);
                o.y = f2bf(acc[i][j][1] * sK[h * SS + tb + 1]);
                o.z = f2bf(acc[i][j][2] * sK[h * SS + tb + 2]);
                o.w = f2bf(acc[i][j][3] * sK[h * SS + tb + 3]);
                *(short4*)&Ob[(size_t)d * SS + tb] = o;
            }
    } else {
        short* __restrict__ Ob = Vtb + (size_t)bh * HD * SS;
#pragma unroll
        for (int i = 0; i < 4; i++)
#pragma unroll
            for (int j = 0; j < 4; j++) {
                const int tb = s0 + wr + i * 16 + r0;
                const int e = wc + j * 16 + c;
                short4 o;
                o.x = f2bf(acc[i][j][0]); o.y = f2bf(acc[i][j][1]);
                o.z = f2bf(acc[i][j][2]); o.w = f2bf(acc[i][j][3]);
                *(short4*)&Ob[(size_t)e * SS + tb] = o;
            }
    }
}

// ---------------- KV: Mp[bid][e][d] = V_chunk^T K'_chunk (MFMA, split-4 over t) -----
__global__ __launch_bounds__(256) void g_kv(
    const short* __restrict__ Vtb, const short* __restrict__ Ktb, float* __restrict__ Mp)
{
    __shared__ short As[2 * 4096], Bs[2 * 4096];
    f32x4 acc[4][4];
    const int bid = blockIdx.x;
    const int chunk = bid & 3, bh = bid >> 2;
    gemm_tile_g(Vtb + (size_t)bh * HD * SS + chunk * 256, SS,
                Ktb + (size_t)bh * HD * SS + chunk * 256, SS, 256, As, Bs, acc);
    const int tid = threadIdx.x, lane = tid & 63, wid = tid >> 6;
    const int wr = (wid >> 1) * 64, wc = (wid & 1) * 64;
    const int r0 = (lane >> 4) * 4, c = lane & 15;
    float* __restrict__ Ob = Mp + (size_t)bid * HD * HD;
#pragma unroll
    for (int i = 0; i < 4; i++)
#pragma unroll
        for (int j = 0; j < 4; j++)
#pragma unroll
            for (int r = 0; r < 4; r++)
                Ob[(size_t)(wr + i * 16 + r0 + r) * HD + wc + j * 16 + c] = acc[i][j][r];
}

// ---------------- reduce 4 chunks + cvt: Mtb[bh][e][d] bf16 ----------------
__global__ __launch_bounds__(256) void g_mredcvt(const float* __restrict__ Mp, short* __restrict__ Mtb) {
    const size_t i = ((size_t)blockIdx.x * 256 + threadIdx.x) * 8;
    const size_t bh = i >> 14, ij = i & 16383;
    const float* p = Mp + (bh * 4) * 16384 + ij;
    float s[8];
#pragma unroll
    for (int q = 0; q < 8; q++) s[q] = 0.f;
#pragma unroll
    for (int cth = 0; cth < 4; cth++) {
        float4 a = *(const float4*)&p[cth * 16384];
        float4 b = *(const float4*)&p[cth * 16384 + 4];
        s[0] += a.x; s[1] += a.y; s[2] += a.z; s[3] += a.w;
        s[4] += b.x; s[5] += b.y; s[6] += b.z; s[7] += b.w;
    }
    bf16x8 v;
#pragma unroll
    for (int q = 0; q < 8; q++) v[q] = f2bf(s[q]);
    *(bf16x8*)&Mtb[i] = v;
}

// ---------- QM: retc[b*S+s][h*128+e] = Q' @ M (MFMA, bf16, concat-heads layout)
//            + fused group-stat atomics ----------
__global__ __launch_bounds__(256) void g_qm(
    const short* __restrict__ Qb, const short* __restrict__ Mtb,
    short* __restrict__ retc, float* __restrict__ Sp)
{
    __shared__ short As[2 * 4096], Bs[2 * 4096];
    f32x4 acc[4][4];
    const int bh = blockIdx.y, m0 = blockIdx.x * 128;
    gemm_tile_g(Qb + ((size_t)bh * SS + m0) * HD, HD,
                Mtb + (size_t)bh * HD * HD, HD, HD, As, Bs, acc);
    const int tid = threadIdx.x, lane = tid & 63, wid = tid >> 6;
    const int wr = (wid >> 1) * 64, wc = (wid & 1) * 64;
    const int r0 = (lane >> 4) * 4, c = lane & 15;
    const int b_ = bh >> 3, h_ = bh & 7;
    // write into concat-heads layout: row = b*S + s, col = h*128 + e
    short* __restrict__ O = retc + ((size_t)(b_ * SS + m0)) * DD + h_ * HD;
#pragma unroll
    for (int i = 0; i < 4; i++)
#pragma unroll
        for (int j = 0; j < 4; j++)
#pragma unroll
            for (int r = 0; r < 4; r++)
                O[(size_t)(wr + i * 16 + r0 + r) * DD + wc + j * 16 + c] = f2bf(acc[i][j][r]);

    // fused group stats: reduce over lane bits {0,1,2} (cols within group-of-8)
    // and {4,5} (row groups): masks {1,2,4,16,32}. Lane bit 3 = column-group half.
    float psm[4], psq[4];
#pragma unroll
    for (int j = 0; j < 4; j++) { psm[j] = 0.f; psq[j] = 0.f; }
#pragma unroll
    for (int i = 0; i < 4; i++)
#pragma unroll
        for (int j = 0; j < 4; j++)
#pragma unroll
            for (int r = 0; r < 4; r++) {
                const float v = acc[i][j][r];
                psm[j] += v; psq[j] += v * v;
            }
    const int masks[5] = {1, 2, 4, 16, 32};
#pragma unroll
    for (int mk = 0; mk < 5; mk++) {
#pragma unroll
        for (int j = 0; j < 4; j++) {
            psm[j] += __shfl_xor(psm[j], masks[mk], 64);
            psq[j] += __shfl_xor(psq[j], masks[mk], 64);
        }
    }
    if ((lane & 7) == 0 && lane < 16) {      // lanes 0 (hi=0) and 8 (hi=1)
        const int hi = lane >> 3;
#pragma unroll
        for (int j = 0; j < 4; j++) {
            const int g = b_ * 128 + h_ * 16 + (wid & 1) * 8 + j * 2 + hi;
            atomicAdd(&Sp[g * 2 + 0], psm[j]);
            atomicAdd(&Sp[g * 2 + 1], psq[j]);
        }
    }
}

// ---------------- gate GEMM + fused GN×gate epilogue: Ab = relu(x@Wg) ⊙ GN(ret) -----
__global__ __launch_bounds__(256) void g_gate(
    const short* __restrict__ xb, const short* __restrict__ WgT,
    const short* __restrict__ retc, const float* __restrict__ Sp,
    const float* __restrict__ gng, const float* __restrict__ gnb,
    short* __restrict__ Ab)
{
    __shared__ short As[2 * 4096], Bs[2 * 4096];
    f32x4 acc[4][4];
    const int n0 = blockIdx.x * 128, m0 = blockIdx.y * 128;
    gemm_tile_g(xb + (size_t)m0 * DD, DD, WgT + (size_t)n0 * DD, DD, DD, As, Bs, acc);
    const int tid = threadIdx.x, lane = tid & 63, wid = tid >> 6;
    const int wr = (wid >> 1) * 64, wc = (wid & 1) * 64;
    const int r0 = (lane >> 4) * 4, c = lane & 15;
    const int b_ = m0 >> 10;
#pragma unroll
    for (int j = 0; j < 4; j++) {
        const int n = n0 + wc + j * 16 + c;
        const int g = b_ * 128 + (n >> 3);
        const float sm = Sp[g * 2 + 0], sq = Sp[g * 2 + 1];
        const float mu = sm * (1.0f / 8192.0f);
        float var = sq * (1.0f / 8192.0f) - mu * mu;
        if (var < 0.f) var = 0.f;
        const float rs = rsqrtf(var + GN_EPS);
        const float gam = gng[n], bet = gnb[n];
#pragma unroll
        for (int i = 0; i < 4; i++)
#pragma unroll
            for (int r = 0; r < 4; r++) {
                const int m = m0 + wr + i * 16 + r0 + r;
                const float rv = bf2f(retc[(size_t)m * DD + n]);   // same tiling as output
                const float y = (rv - mu) * rs * gam + bet;
                const float gate = fmaxf(acc[i][j][r], 0.f);
                Ab[(size_t)m * DD + n] = f2bf(gate * y);
            }
    }
}

// ---------------- final GEMM: out = Ab @ WoT^T (MFMA, f32 out) ----------------
__global__ __launch_bounds__(256) void g_final(
    const short* __restrict__ Ab, const short* __restrict__ WoT, float* __restrict__ out)
{
    __shared__ short As[2 * 4096], Bs[2 * 4096];
    f32x4 acc[4][4];
    const int n0 = blockIdx.x * 128, m0 = blockIdx.y * 128;
    gemm_tile_g(Ab + (size_t)m0 * DD, DD, WoT + (size_t)n0 * DD, DD, DD, As, Bs, acc);
    const int tid = threadIdx.x, lane = tid & 63, wid = tid >> 6;
    const int wr = (wid >> 1) * 64, wc = (wid & 1) * 64;
    const int r0 = (lane >> 4) * 4, c = lane & 15;
#pragma unroll
    for (int i = 0; i < 4; i++)
#pragma unroll
        for (int j = 0; j < 4; j++)
#pragma unroll
            for (int r = 0; r < 4; r++)
                out[(size_t)(m0 + wr + i * 16 + r0 + r) * DD + n0 + wc + j * 16 + c] = acc[i][j][r];
}

extern "C" void kernel_launch(void* const* d_in, const int* in_sizes, int n_in,
                              void* d_out, int out_size, void* d_ws, size_t ws_size,
                              hipStream_t stream)
{
    const float* x   = (const float*)d_in[0];
    const float* Wq  = (const float*)d_in[1];
    const float* Wk  = (const float*)d_in[2];
    const float* Wv  = (const float*)d_in[3];
    const float* Wg  = (const float*)d_in[4];
    const float* Wo  = (const float*)d_in[5];
    const float* gng = (const float*)d_in[6];
    const float* gnb = (const float*)d_in[7];
    float* out = (float*)d_out;

    char* ws = (char*)d_ws;
    size_t off = 0;
    auto alloc = [&](size_t bytes) -> void* {
        void* p = ws + off;
        off += (bytes + 255) & ~(size_t)255;
        return p;
    };
    const size_t NE = (size_t)BB * SS * DD;   // 8,388,608
    float*  sQ    = (float*)alloc((size_t)HH * SS * sizeof(float));
    float*  sK    = (float*)alloc((size_t)HH * SS * sizeof(float));
    short*  xb    = (short*)alloc(NE * sizeof(short));
    short*  WgT   = (short*)alloc((size_t)DD * DD * sizeof(short));
    short*  WoT   = (short*)alloc((size_t)DD * DD * sizeof(short));
    short*  Wt    = (short*)alloc((size_t)24 * HD * HD * sizeof(short));
    short*  Qb    = (short*)alloc(NE * sizeof(short));
    short*  Ktb   = (short*)alloc(NE * sizeof(short));
    short*  Vtb   = (short*)alloc(NE * sizeof(short));
    short*  retc  = (short*)alloc(NE * sizeof(short));
    short*  Ab    = (short*)alloc(NE * sizeof(short));
    float*  Mp    = (float*)alloc((size_t)256 * HD * HD * sizeof(float));
    short*  Mtb   = (short*)alloc((size_t)64 * HD * HD * sizeof(short));
    float*  Sp    = (float*)alloc((size_t)1024 * 2 * sizeof(float));

    prep<<<dim3(6561), 256, 0, stream>>>(x, Wq, Wk, Wv, Wg, Wo, xb, WgT, WoT, Wt, sQ, sK, Sp);
    g_qkv<<<dim3(64, 24), 256, 0, stream>>>(xb, Wt, sQ, sK, Qb, Ktb, Vtb);
    g_kv<<<dim3(256), 256, 0, stream>>>(Vtb, Ktb, Mp);
    g_mredcvt<<<dim3(512), 256, 0, stream>>>(Mp, Mtb);
    g_qm<<<dim3(8, 64), 256, 0, stream>>>(Qb, Mtb, retc, Sp);
    g_gate<<<dim3(8, 64), 256, 0, stream>>>(xb, WgT, retc, Sp, gng, gnb, Ab);
    g_final<<<dim3(8, 64), 256, 0, stream>>>(Ab, WoT, out);
}

// Round 9
// 136.643 us; speedup vs baseline: 5.0345x; 1.0333x over previous
//
#include <hip/hip_runtime.h>

#define BB 8
#define SS 1024
#define DD 1024
#define HH 8
#define HD 128
#define GN_EPS 1e-3f

typedef __attribute__((ext_vector_type(8))) short bf16x8;
typedef __attribute__((ext_vector_type(4))) float f32x4;

__device__ __forceinline__ short f2bf(float f) {
    unsigned u = __float_as_uint(f);
    return (short)((u + 0x7fffu + ((u >> 16) & 1u)) >> 16);
}
__device__ __forceinline__ float bf2f(short s) {
    return __uint_as_float(((unsigned)(unsigned short)s) << 16);
}

__device__ __forceinline__ void gload16(const void* g, void* l) {
    __builtin_amdgcn_global_load_lds((const __attribute__((address_space(1))) void*)g,
                                     (__attribute__((address_space(3))) void*)l, 16, 0, 0);
}

// ---- stage one 128x32-short tile (8 KB) via global_load_lds, linear row-major LDS ----
__device__ __forceinline__ void stage_tile(const short* __restrict__ G, size_t ld, int k0,
                                           short* lds, int wid, int lane) {
#pragma unroll
    for (int i = 0; i < 2; i++) {
        const int seg = wid * 2 + i;
        const int row = seg * 16 + (lane >> 2);
        gload16(G + (size_t)row * ld + k0 + (lane & 3) * 8, lds + seg * 512);
    }
}

// ---------------- 128x128xK MFMA tile core: global_load_lds + LDS double-buffer ------
__device__ __forceinline__ void gemm_tile_g(
    const short* __restrict__ A, size_t ldA,
    const short* __restrict__ B, size_t ldB,
    int K, short* As, short* Bs, f32x4 acc[4][4])
{
    const int tid = threadIdx.x, lane = tid & 63, wid = tid >> 6;
    const int wr = (wid >> 1) * 64, wc = (wid & 1) * 64;
    const int fr = lane & 15, fk = (lane >> 4) * 8;
#pragma unroll
    for (int i = 0; i < 4; i++)
#pragma unroll
        for (int j = 0; j < 4; j++) acc[i][j] = (f32x4){0.f, 0.f, 0.f, 0.f};

    stage_tile(A, ldA, 0, As, wid, lane);
    stage_tile(B, ldB, 0, Bs, wid, lane);
    __syncthreads();
    const int nt = K >> 5;
    int cur = 0;
    for (int t = 0; t < nt; t++) {
        if (t + 1 < nt) {
            stage_tile(A, ldA, (t + 1) << 5, As + ((cur ^ 1) << 12), wid, lane);
            stage_tile(B, ldB, (t + 1) << 5, Bs + ((cur ^ 1) << 12), wid, lane);
        }
        const short* as = As + (cur << 12);
        const short* bs = Bs + (cur << 12);
        bf16x8 af[4], bfv[4];
#pragma unroll
        for (int i = 0; i < 4; i++) af[i] = *(const bf16x8*)&as[(wr + i * 16 + fr) * 32 + fk];
#pragma unroll
        for (int j = 0; j < 4; j++) bfv[j] = *(const bf16x8*)&bs[(wc + j * 16 + fr) * 32 + fk];
#pragma unroll
        for (int i = 0; i < 4; i++)
#pragma unroll
            for (int j = 0; j < 4; j++)
                acc[i][j] = __builtin_amdgcn_mfma_f32_16x16x32_bf16(af[i], bfv[j], acc[i][j], 0, 0, 0);
        __syncthreads();
        cur ^= 1;
    }
}

// ---------------- prep: x->bf16, W transposes, scales, zero Sp ----------------
__global__ __launch_bounds__(256) void prep(
    const float* __restrict__ x,
    const float* __restrict__ Wq, const float* __restrict__ Wk, const float* __restrict__ Wv,
    const float* __restrict__ Wg, const float* __restrict__ Wo,
    short* __restrict__ xb, short* __restrict__ WgT, short* __restrict__ WoT,
    short* __restrict__ Wt, float* __restrict__ sQ, float* __restrict__ sK,
    float* __restrict__ Sp)
{
    __shared__ float t[32][33];
    int bid = blockIdx.x;
    const int tid = threadIdx.x;
    if (bid < 4096) {                       // x -> bf16 flat
        const size_t i = ((size_t)bid * 256 + tid) * 8;
        float4 a = *(const float4*)&x[i];
        float4 b = *(const float4*)&x[i + 4];
        bf16x8 v;
        v[0] = f2bf(a.x); v[1] = f2bf(a.y); v[2] = f2bf(a.z); v[3] = f2bf(a.w);
        v[4] = f2bf(b.x); v[5] = f2bf(b.y); v[6] = f2bf(b.z); v[7] = f2bf(b.w);
        *(bf16x8*)&xb[i] = v;
        return;
    }
    bid -= 4096;
    if (bid < 2048) {                       // Wg / Wo transpose -> bf16
        const float* __restrict__ S = (bid < 1024) ? Wg : Wo;
        short* __restrict__ D = (bid < 1024) ? WgT : WoT;
        const int tb = bid & 1023;
        const int bx = (tb & 31) * 32, by = (tb >> 5) * 32;
        const int xx = tid & 31, y0 = tid >> 5;
#pragma unroll
        for (int r = 0; r < 32; r += 8) t[y0 + r][xx] = S[(size_t)(by + y0 + r) * 1024 + bx + xx];
        __syncthreads();
#pragma unroll
        for (int r = 0; r < 32; r += 8) D[(size_t)(bx + y0 + r) * 1024 + by + xx] = f2bf(t[xx][y0 + r]);
        return;
    }
    bid -= 2048;
    if (bid < 384) {                        // 24 head matrices
        const int ht = bid >> 4, tb = bid & 15;
        const int typ = ht >> 3, h = ht & 7;
        const float* __restrict__ W = (typ == 0 ? Wq : (typ == 1 ? Wk : Wv)) + (size_t)h * HD * HD;
        short* __restrict__ D = Wt + (size_t)ht * HD * HD;
        const int bx = (tb & 3) * 32, by = (tb >> 2) * 32;
        const int xx = tid & 31, y0 = tid >> 5;
#pragma unroll
        for (int r = 0; r < 32; r += 8) t[y0 + r][xx] = W[(by + y0 + r) * HD + bx + xx];
        __syncthreads();
#pragma unroll
        for (int r = 0; r < 32; r += 8) D[(bx + y0 + r) * HD + by + xx] = f2bf(t[xx][y0 + r]);
        return;
    }
    bid -= 384;
    if (bid < 32) {                         // decay scale tables
        const int h = bid >> 2;
        const int s = (bid & 3) * 256 + tid;
        const double gamma = 1.0 - exp2((double)(-5 - h));
        const double lg = log2(gamma);
        sQ[h * SS + s] = (float)exp2(lg * (double)s);
        sK[h * SS + s] = (float)exp2(-lg * (double)s);
        return;
    }
    // last block: zero Sp[2048]
    *(float4*)&Sp[tid * 8] = (float4){0.f, 0.f, 0.f, 0.f};
    *(float4*)&Sp[tid * 8 + 4] = (float4){0.f, 0.f, 0.f, 0.f};
}

// ---- QKV + gate GEMM in one dispatch (2048 blocks, XCD-chunked work assignment) ----
// chunk cx = orig&7 (XCD), pos p = orig>>3 (0..255).
// p <  64: gate role, w2 = cx*64 + p   (dispatched FIRST: long-K blocks start early)
// p >= 64: qkv role,  w  = cx*192 + (p-64)
__global__ __launch_bounds__(256) void g_qkvgate(
    const short* __restrict__ xb, const short* __restrict__ Wt, const short* __restrict__ WgT,
    const float* __restrict__ sQ, const float* __restrict__ sK,
    short* __restrict__ Qb, short* __restrict__ Ktb, short* __restrict__ Vtb,
    short* __restrict__ gateb)
{
    __shared__ short As[2 * 4096], Bs[2 * 4096];
    f32x4 acc[4][4];
    const int orig = blockIdx.x;
    const int cx = orig & 7, p = orig >> 3;
    const int tid = threadIdx.x, lane = tid & 63, wid = tid >> 6;
    const int wr = (wid >> 1) * 64, wc = (wid & 1) * 64;
    const int r0 = (lane >> 4) * 4, c = lane & 15;

    if (p < 64) {
        // ---------------- gate GEMM: gateb = ReLU(xb @ WgT^T) bf16 ----------------
        const int w2 = cx * 64 + p;                 // 0..511, mt-major within chunk
        const int m0 = (w2 >> 3) * 128, n0 = (w2 & 7) * 128;
        gemm_tile_g(xb + (size_t)m0 * DD, DD, WgT + (size_t)n0 * DD, DD, DD, As, Bs, acc);
#pragma unroll
        for (int i = 0; i < 4; i++)
#pragma unroll
            for (int j = 0; j < 4; j++)
#pragma unroll
                for (int r = 0; r < 4; r++)
                    gateb[(size_t)(m0 + wr + i * 16 + r0 + r) * DD + n0 + wc + j * 16 + c] =
                        f2bf(fmaxf(acc[i][j][r], 0.f));
        return;
    }
    // ---------------- QKV ----------------
    const int w = cx * 192 + (p - 64);              // 0..1535: ht = w>>6 (3 per chunk)
    const int ht = w >> 6, mt = w & 63;
    const int m0 = mt * 128;
    const int typ = ht >> 3, h = ht & 7;
    gemm_tile_g(xb + (size_t)m0 * DD + h * HD, DD,
                Wt + (size_t)ht * HD * HD, HD, HD, As, Bs, acc);
    const int b = m0 >> 10, s0 = m0 & (SS - 1);
    const int bh = (b << 3) + h;
    if (typ == 0) {
#pragma unroll
        for (int i = 0; i < 4; i++)
#pragma unroll
            for (int j = 0; j < 4; j++)
#pragma unroll
                for (int r = 0; r < 4; r++) {
                    const int s = s0 + wr + i * 16 + r0 + r;
                    Qb[((size_t)bh * SS + s) * HD + wc + j * 16 + c] =
                        f2bf(acc[i][j][r] * sQ[h * SS + s]);
                }
    } else if (typ == 1) {
        short* __restrict__ Ob = Ktb + (size_t)bh * HD * SS;
#pragma unroll
        for (int i = 0; i < 4; i++)
#pragma unroll
            for (int j = 0; j < 4; j++) {
                const int tb = s0 + wr + i * 16 + r0;
                const int d = wc + j * 16 + c;
                short4 o;
                o.x = f2bf(acc[i][j][0] * sK[h * SS + tb + 0]);
                o.y = f2bf(acc[i][j][1] * sK[h * SS + tb + 1]);
                o.z = f2bf(acc[i][j][2] * sK[h * SS + tb + 2]);
                o.w = f2bf(acc[i][j][3] * sK[h * SS + tb + 3]);
                *(short4*)&Ob[(size_t)d * SS + tb] = o;
            }
    } else {
        short* __restrict__ Ob = Vtb + (size_t)bh * HD * SS;
#pragma unroll
        for (int i = 0; i < 4; i++)
#pragma unroll
            for (int j = 0; j < 4; j++) {
                const int tb = s0 + wr + i * 16 + r0;
                const int e = wc + j * 16 + c;
                short4 o;
                o.x = f2bf(acc[i][j][0]); o.y = f2bf(acc[i][j][1]);
                o.z = f2bf(acc[i][j][2]); o.w = f2bf(acc[i][j][3]);
                *(short4*)&Ob[(size_t)e * SS + tb] = o;
            }
    }
}

// ---------------- KV: Mp[w][e][d] = V_chunk^T K'_chunk (MFMA, split-4, swizzled) ----
__global__ __launch_bounds__(256) void g_kv(
    const short* __restrict__ Vtb, const short* __restrict__ Ktb, float* __restrict__ Mp)
{
    __shared__ short As[2 * 4096], Bs[2 * 4096];
    f32x4 acc[4][4];
    const int orig = blockIdx.x;                    // 256
    const int w = (orig & 7) * 32 + (orig >> 3);
    const int chunk = w & 3, bh = w >> 2;
    gemm_tile_g(Vtb + (size_t)bh * HD * SS + chunk * 256, SS,
                Ktb + (size_t)bh * HD * SS + chunk * 256, SS, 256, As, Bs, acc);
    const int tid = threadIdx.x, lane = tid & 63, wid = tid >> 6;
    const int wr = (wid >> 1) * 64, wc = (wid & 1) * 64;
    const int r0 = (lane >> 4) * 4, c = lane & 15;
    float* __restrict__ Ob = Mp + (size_t)w * HD * HD;
#pragma unroll
    for (int i = 0; i < 4; i++)
#pragma unroll
        for (int j = 0; j < 4; j++)
#pragma unroll
            for (int r = 0; r < 4; r++)
                Ob[(size_t)(wr + i * 16 + r0 + r) * HD + wc + j * 16 + c] = acc[i][j][r];
}

// ---------------- reduce 4 chunks + cvt: Mtb[bh][e][d] bf16 ----------------
__global__ __launch_bounds__(256) void g_mredcvt(const float* __restrict__ Mp, short* __restrict__ Mtb) {
    const size_t i = ((size_t)blockIdx.x * 256 + threadIdx.x) * 8;
    const size_t bh = i >> 14, ij = i & 16383;
    const float* p = Mp + (bh * 4) * 16384 + ij;
    float s[8];
#pragma unroll
    for (int q = 0; q < 8; q++) s[q] = 0.f;
#pragma unroll
    for (int cth = 0; cth < 4; cth++) {
        float4 a = *(const float4*)&p[cth * 16384];
        float4 b = *(const float4*)&p[cth * 16384 + 4];
        s[0] += a.x; s[1] += a.y; s[2] += a.z; s[3] += a.w;
        s[4] += b.x; s[5] += b.y; s[6] += b.z; s[7] += b.w;
    }
    bf16x8 v;
#pragma unroll
    for (int q = 0; q < 8; q++) v[q] = f2bf(s[q]);
    *(bf16x8*)&Mtb[i] = v;
}

// ---------- QM: retc[b*S+s][h*128+e] = Q' @ M (MFMA, bf16, concat-heads layout)
//            + fused group-stat atomics (XCD-chunked grid) ----------
__global__ __launch_bounds__(256) void g_qm(
    const short* __restrict__ Qb, const short* __restrict__ Mtb,
    short* __restrict__ retc, float* __restrict__ Sp)
{
    __shared__ short As[2 * 4096], Bs[2 * 4096];
    f32x4 acc[4][4];
    const int orig = blockIdx.x;                    // 512
    const int w = (orig & 7) * 64 + (orig >> 3);
    const int bh = w >> 3, m0 = (w & 7) * 128;
    gemm_tile_g(Qb + ((size_t)bh * SS + m0) * HD, HD,
                Mtb + (size_t)bh * HD * HD, HD, HD, As, Bs, acc);
    const int tid = threadIdx.x, lane = tid & 63, wid = tid >> 6;
    const int wr = (wid >> 1) * 64, wc = (wid & 1) * 64;
    const int r0 = (lane >> 4) * 4, c = lane & 15;
    const int b_ = bh >> 3, h_ = bh & 7;
    short* __restrict__ O = retc + ((size_t)(b_ * SS + m0)) * DD + h_ * HD;
#pragma unroll
    for (int i = 0; i < 4; i++)
#pragma unroll
        for (int j = 0; j < 4; j++)
#pragma unroll
            for (int r = 0; r < 4; r++)
                O[(size_t)(wr + i * 16 + r0 + r) * DD + wc + j * 16 + c] = f2bf(acc[i][j][r]);

    // fused group stats: reduce over lane bits {0,1,2} and {4,5}: masks {1,2,4,16,32}
    float psm[4], psq[4];
#pragma unroll
    for (int j = 0; j < 4; j++) { psm[j] = 0.f; psq[j] = 0.f; }
#pragma unroll
    for (int i = 0; i < 4; i++)
#pragma unroll
        for (int j = 0; j < 4; j++)
#pragma unroll
            for (int r = 0; r < 4; r++) {
                const float v = acc[i][j][r];
                psm[j] += v; psq[j] += v * v;
            }
    const int masks[5] = {1, 2, 4, 16, 32};
#pragma unroll
    for (int mk = 0; mk < 5; mk++) {
#pragma unroll
        for (int j = 0; j < 4; j++) {
            psm[j] += __shfl_xor(psm[j], masks[mk], 64);
            psq[j] += __shfl_xor(psq[j], masks[mk], 64);
        }
    }
    if ((lane & 7) == 0 && lane < 16) {
        const int hi = lane >> 3;
#pragma unroll
        for (int j = 0; j < 4; j++) {
            const int g = b_ * 128 + h_ * 16 + (wid & 1) * 8 + j * 2 + hi;
            atomicAdd(&Sp[g * 2 + 0], psm[j]);
            atomicAdd(&Sp[g * 2 + 1], psq[j]);
        }
    }
}

// ---------------- aprep: Ab = gateb ⊙ GN(retc) -> bf16 (both layouts coalesced) -----
__global__ __launch_bounds__(256) void aprep(
    const short* __restrict__ gateb, const short* __restrict__ retc,
    const float* __restrict__ Sp,
    const float* __restrict__ gng, const float* __restrict__ gnb, short* __restrict__ Ab)
{
    const size_t idx = ((size_t)blockIdx.x * 256 + threadIdx.x) * 4;
    const int m = (int)(idx >> 10), cc = (int)(idx & 1023);
    const int b_ = m >> 10, g = b_ * 128 + (cc >> 3);
    const float sm = Sp[g * 2 + 0], sq = Sp[g * 2 + 1];
    const float mu = sm * (1.0f / 8192.0f);
    float var = sq * (1.0f / 8192.0f) - mu * mu;
    if (var < 0.f) var = 0.f;
    const float rs = rsqrtf(var + GN_EPS);
    short4 gv4 = *(const short4*)&gateb[idx];
    short4 rv4 = *(const short4*)&retc[idx];
    float4 gv = *(const float4*)&gng[cc];
    float4 bv = *(const float4*)&gnb[cc];
    short4 o;
    o.x = f2bf(bf2f(gv4.x) * ((bf2f(rv4.x) - mu) * rs * gv.x + bv.x));
    o.y = f2bf(bf2f(gv4.y) * ((bf2f(rv4.y) - mu) * rs * gv.y + bv.y));
    o.z = f2bf(bf2f(gv4.z) * ((bf2f(rv4.z) - mu) * rs * gv.z + bv.z));
    o.w = f2bf(bf2f(gv4.w) * ((bf2f(rv4.w) - mu) * rs * gv.w + bv.w));
    *(short4*)&Ab[idx] = o;
}

// ---------------- final GEMM: out = Ab @ WoT^T (MFMA, f32 out, XCD-chunked) ---------
__global__ __launch_bounds__(256) void g_final(
    const short* __restrict__ Ab, const short* __restrict__ WoT, float* __restrict__ out)
{
    __shared__ short As[2 * 4096], Bs[2 * 4096];
    f32x4 acc[4][4];
    const int orig = blockIdx.x;                    // 512
    const int w = (orig & 7) * 64 + (orig >> 3);    // mt-major within chunk
    const int m0 = (w >> 3) * 128, n0 = (w & 7) * 128;
    gemm_tile_g(Ab + (size_t)m0 * DD, DD, WoT + (size_t)n0 * DD, DD, DD, As, Bs, acc);
    const int tid = threadIdx.x, lane = tid & 63, wid = tid >> 6;
    const int wr = (wid >> 1) * 64, wc = (wid & 1) * 64;
    const int r0 = (lane >> 4) * 4, c = lane & 15;
#pragma unroll
    for (int i = 0; i < 4; i++)
#pragma unroll
        for (int j = 0; j < 4; j++)
#pragma unroll
            for (int r = 0; r < 4; r++)
                out[(size_t)(m0 + wr + i * 16 + r0 + r) * DD + n0 + wc + j * 16 + c] = acc[i][j][r];
}

extern "C" void kernel_launch(void* const* d_in, const int* in_sizes, int n_in,
                              void* d_out, int out_size, void* d_ws, size_t ws_size,
                              hipStream_t stream)
{
    const float* x   = (const float*)d_in[0];
    const float* Wq  = (const float*)d_in[1];
    const float* Wk  = (const float*)d_in[2];
    const float* Wv  = (const float*)d_in[3];
    const float* Wg  = (const float*)d_in[4];
    const float* Wo  = (const float*)d_in[5];
    const float* gng = (const float*)d_in[6];
    const float* gnb = (const float*)d_in[7];
    float* out = (float*)d_out;

    char* ws = (char*)d_ws;
    size_t off = 0;
    auto alloc = [&](size_t bytes) -> void* {
        void* p = ws + off;
        off += (bytes + 255) & ~(size_t)255;
        return p;
    };
    const size_t NE = (size_t)BB * SS * DD;   // 8,388,608
    float*  sQ    = (float*)alloc((size_t)HH * SS * sizeof(float));
    float*  sK    = (float*)alloc((size_t)HH * SS * sizeof(float));
    short*  xb    = (short*)alloc(NE * sizeof(short));
    short*  WgT   = (short*)alloc((size_t)DD * DD * sizeof(short));
    short*  WoT   = (short*)alloc((size_t)DD * DD * sizeof(short));
    short*  Wt    = (short*)alloc((size_t)24 * HD * HD * sizeof(short));
    short*  Qb    = (short*)alloc(NE * sizeof(short));
    short*  Ktb   = (short*)alloc(NE * sizeof(short));
    short*  Vtb   = (short*)alloc(NE * sizeof(short));
    short*  retc  = (short*)alloc(NE * sizeof(short));
    short*  gateb = (short*)alloc(NE * sizeof(short));
    short*  Ab    = (short*)alloc(NE * sizeof(short));
    float*  Mp    = (float*)alloc((size_t)256 * HD * HD * sizeof(float));
    short*  Mtb   = (short*)alloc((size_t)64 * HD * HD * sizeof(short));
    float*  Sp    = (float*)alloc((size_t)1024 * 2 * sizeof(float));

    prep<<<dim3(6561), 256, 0, stream>>>(x, Wq, Wk, Wv, Wg, Wo, xb, WgT, WoT, Wt, sQ, sK, Sp);
    g_qkvgate<<<dim3(2048), 256, 0, stream>>>(xb, Wt, WgT, sQ, sK, Qb, Ktb, Vtb, gateb);
    g_kv<<<dim3(256), 256, 0, stream>>>(Vtb, Ktb, Mp);
    g_mredcvt<<<dim3(512), 256, 0, stream>>>(Mp, Mtb);
    g_qm<<<dim3(512), 256, 0, stream>>>(Qb, Mtb, retc, Sp);
    aprep<<<dim3(8192), 256, 0, stream>>>(gateb, retc, Sp, gng, gnb, Ab);
    g_final<<<dim3(512), 256, 0, stream>>>(Ab, WoT, out);
}

// Round 10
// 128.993 us; speedup vs baseline: 5.3331x; 1.0593x over previous
//
#include <hip/hip_runtime.h>

#define BB 8
#define SS 1024
#define DD 1024
#define HH 8
#define HD 128
#define GN_EPS 1e-3f

typedef __attribute__((ext_vector_type(8))) short bf16x8;
typedef __attribute__((ext_vector_type(4))) float f32x4;

__device__ __forceinline__ short f2bf(float f) {
    unsigned u = __float_as_uint(f);
    return (short)((u + 0x7fffu + ((u >> 16) & 1u)) >> 16);
}
__device__ __forceinline__ float bf2f(short s) {
    return __uint_as_float(((unsigned)(unsigned short)s) << 16);
}

__device__ __forceinline__ void gload16(const void* g, void* l) {
    __builtin_amdgcn_global_load_lds((const __attribute__((address_space(1))) void*)g,
                                     (__attribute__((address_space(3))) void*)l, 16, 0, 0);
}

// ---- stage one 128x64-short tile (16 KB) via global_load_lds ----
// LDS layout: linear [row][8 chunks of 8 shorts], 128 B/row. Content is chunk-swizzled:
// slot q of row r holds GLOBAL chunk q ^ (r&7)  (pre-swizzled global source address;
// gload_lds dest stays linear: base + lane*16B). Read side applies the same XOR.
__device__ __forceinline__ void stage_tile(const short* __restrict__ G, size_t ld, int k0,
                                           short* lds, int wid, int lane) {
#pragma unroll
    for (int i = 0; i < 4; i++) {
        const int seg = wid * 4 + i;                 // 0..15 (8 rows each)
        const int row = seg * 8 + (lane >> 3);       // 0..127
        const int chunk = (lane & 7) ^ (lane >> 3);  // = (slot) ^ (row&7)
        gload16(G + (size_t)row * ld + k0 + chunk * 8, lds + seg * 512);
    }
}

// ---------------- 128x128xK MFMA tile core: BK=64, gload_lds + LDS double-buffer ----
// A: [128 rows][K] k-contiguous bf16 ; B: [128 cols][K] k-contiguous bf16
// As/Bs: 2 * 8192 shorts each (32 KB each, 64 KB total).
__device__ __forceinline__ void gemm_tile_g(
    const short* __restrict__ A, size_t ldA,
    const short* __restrict__ B, size_t ldB,
    int K, short* As, short* Bs, f32x4 acc[4][4])
{
    const int tid = threadIdx.x, lane = tid & 63, wid = tid >> 6;
    const int wr = (wid >> 1) * 64, wc = (wid & 1) * 64;
    const int fr = lane & 15, fc = lane >> 4;        // fc: 16B-chunk index base (0..3)
    const int rsw = fr & 7;                          // row&7 for all this lane's frag rows
#pragma unroll
    for (int i = 0; i < 4; i++)
#pragma unroll
        for (int j = 0; j < 4; j++) acc[i][j] = (f32x4){0.f, 0.f, 0.f, 0.f};

    stage_tile(A, ldA, 0, As, wid, lane);
    stage_tile(B, ldB, 0, Bs, wid, lane);
    __syncthreads();
    const int nt = K >> 6;
    int cur = 0;
    for (int t = 0; t < nt; t++) {
        if (t + 1 < nt) {
            stage_tile(A, ldA, (t + 1) << 6, As + ((cur ^ 1) << 13), wid, lane);
            stage_tile(B, ldB, (t + 1) << 6, Bs + ((cur ^ 1) << 13), wid, lane);
        }
        const short* as = As + (cur << 13);
        const short* bs = Bs + (cur << 13);
#pragma unroll
        for (int half = 0; half < 2; half++) {
            const int slot = ((half * 4 + fc) ^ rsw) << 3;   // swizzled 8-short slot
            bf16x8 af[4], bfv[4];
#pragma unroll
            for (int i = 0; i < 4; i++) af[i] = *(const bf16x8*)&as[(wr + i * 16 + fr) * 64 + slot];
#pragma unroll
            for (int j = 0; j < 4; j++) bfv[j] = *(const bf16x8*)&bs[(wc + j * 16 + fr) * 64 + slot];
#pragma unroll
            for (int i = 0; i < 4; i++)
#pragma unroll
                for (int j = 0; j < 4; j++)
                    acc[i][j] = __builtin_amdgcn_mfma_f32_16x16x32_bf16(af[i], bfv[j], acc[i][j], 0, 0, 0);
        }
        __syncthreads();
        cur ^= 1;
    }
}

// ---------------- prep: x->bf16, W transposes, scales, zero Sp ----------------
__global__ __launch_bounds__(256) void prep(
    const float* __restrict__ x,
    const float* __restrict__ Wq, const float* __restrict__ Wk, const float* __restrict__ Wv,
    const float* __restrict__ Wg, const float* __restrict__ Wo,
    short* __restrict__ xb, short* __restrict__ WgT, short* __restrict__ WoT,
    short* __restrict__ Wt, float* __restrict__ sQ, float* __restrict__ sK,
    float* __restrict__ Sp)
{
    __shared__ float t[32][33];
    int bid = blockIdx.x;
    const int tid = threadIdx.x;
    if (bid < 4096) {                       // x -> bf16 flat
        const size_t i = ((size_t)bid * 256 + tid) * 8;
        float4 a = *(const float4*)&x[i];
        float4 b = *(const float4*)&x[i + 4];
        bf16x8 v;
        v[0] = f2bf(a.x); v[1] = f2bf(a.y); v[2] = f2bf(a.z); v[3] = f2bf(a.w);
        v[4] = f2bf(b.x); v[5] = f2bf(b.y); v[6] = f2bf(b.z); v[7] = f2bf(b.w);
        *(bf16x8*)&xb[i] = v;
        return;
    }
    bid -= 4096;
    if (bid < 2048) {                       // Wg / Wo transpose -> bf16
        const float* __restrict__ S = (bid < 1024) ? Wg : Wo;
        short* __restrict__ D = (bid < 1024) ? WgT : WoT;
        const int tb = bid & 1023;
        const int bx = (tb & 31) * 32, by = (tb >> 5) * 32;
        const int xx = tid & 31, y0 = tid >> 5;
#pragma unroll
        for (int r = 0; r < 32; r += 8) t[y0 + r][xx] = S[(size_t)(by + y0 + r) * 1024 + bx + xx];
        __syncthreads();
#pragma unroll
        for (int r = 0; r < 32; r += 8) D[(size_t)(bx + y0 + r) * 1024 + by + xx] = f2bf(t[xx][y0 + r]);
        return;
    }
    bid -= 2048;
    if (bid < 384) {                        // 24 head matrices
        const int ht = bid >> 4, tb = bid & 15;
        const int typ = ht >> 3, h = ht & 7;
        const float* __restrict__ W = (typ == 0 ? Wq : (typ == 1 ? Wk : Wv)) + (size_t)h * HD * HD;
        short* __restrict__ D = Wt + (size_t)ht * HD * HD;
        const int bx = (tb & 3) * 32, by = (tb >> 2) * 32;
        const int xx = tid & 31, y0 = tid >> 5;
#pragma unroll
        for (int r = 0; r < 32; r += 8) t[y0 + r][xx] = W[(by + y0 + r) * HD + bx + xx];
        __syncthreads();
#pragma unroll
        for (int r = 0; r < 32; r += 8) D[(bx + y0 + r) * HD + by + xx] = f2bf(t[xx][y0 + r]);
        return;
    }
    bid -= 384;
    if (bid < 32) {                         // decay scale tables
        const int h = bid >> 2;
        const int s = (bid & 3) * 256 + tid;
        const double gamma = 1.0 - exp2((double)(-5 - h));
        const double lg = log2(gamma);
        sQ[h * SS + s] = (float)exp2(lg * (double)s);
        sK[h * SS + s] = (float)exp2(-lg * (double)s);
        return;
    }
    // last block: zero Sp[2048]
    *(float4*)&Sp[tid * 8] = (float4){0.f, 0.f, 0.f, 0.f};
    *(float4*)&Sp[tid * 8 + 4] = (float4){0.f, 0.f, 0.f, 0.f};
}

// ---- QKV + gate GEMM in one dispatch (2048 blocks, XCD-chunked work assignment) ----
__global__ __launch_bounds__(256) void g_qkvgate(
    const short* __restrict__ xb, const short* __restrict__ Wt, const short* __restrict__ WgT,
    const float* __restrict__ sQ, const float* __restrict__ sK,
    short* __restrict__ Qb, short* __restrict__ Ktb, short* __restrict__ Vtb,
    short* __restrict__ gateb)
{
    __shared__ short As[2 * 8192], Bs[2 * 8192];
    f32x4 acc[4][4];
    const int orig = blockIdx.x;
    const int cx = orig & 7, p = orig >> 3;
    const int tid = threadIdx.x, lane = tid & 63, wid = tid >> 6;
    const int wr = (wid >> 1) * 64, wc = (wid & 1) * 64;
    const int r0 = (lane >> 4) * 4, c = lane & 15;

    if (p < 64) {
        // gate GEMM: gateb = ReLU(xb @ WgT^T) bf16
        const int w2 = cx * 64 + p;
        const int m0 = (w2 >> 3) * 128, n0 = (w2 & 7) * 128;
        gemm_tile_g(xb + (size_t)m0 * DD, DD, WgT + (size_t)n0 * DD, DD, DD, As, Bs, acc);
#pragma unroll
        for (int i = 0; i < 4; i++)
#pragma unroll
            for (int j = 0; j < 4; j++)
#pragma unroll
                for (int r = 0; r < 4; r++)
                    gateb[(size_t)(m0 + wr + i * 16 + r0 + r) * DD + n0 + wc + j * 16 + c] =
                        f2bf(fmaxf(acc[i][j][r], 0.f));
        return;
    }
    // QKV
    const int w = cx * 192 + (p - 64);
    const int ht = w >> 6, mt = w & 63;
    const int m0 = mt * 128;
    const int typ = ht >> 3, h = ht & 7;
    gemm_tile_g(xb + (size_t)m0 * DD + h * HD, DD,
                Wt + (size_t)ht * HD * HD, HD, HD, As, Bs, acc);
    const int b = m0 >> 10, s0 = m0 & (SS - 1);
    const int bh = (b << 3) + h;
    if (typ == 0) {
#pragma unroll
        for (int i = 0; i < 4; i++)
#pragma unroll
            for (int j = 0; j < 4; j++)
#pragma unroll
                for (int r = 0; r < 4; r++) {
                    const int s = s0 + wr + i * 16 + r0 + r;
                    Qb[((size_t)bh * SS + s) * HD + wc + j * 16 + c] =
                        f2bf(acc[i][j][r] * sQ[h * SS + s]);
                }
    } else if (typ == 1) {
        short* __restrict__ Ob = Ktb + (size_t)bh * HD * SS;
#pragma unroll
        for (int i = 0; i < 4; i++)
#pragma unroll
            for (int j = 0; j < 4; j++) {
                const int tb = s0 + wr + i * 16 + r0;
                const int d = wc + j * 16 + c;
                short4 o;
                o.x = f2bf(acc[i][j][0] * sK[h * SS + tb + 0]);
                o.y = f2bf(acc[i][j][1] * sK[h * SS + tb + 1]);
                o.z = f2bf(acc[i][j][2] * sK[h * SS + tb + 2]);
                o.w = f2bf(acc[i][j][3] * sK[h * SS + tb + 3]);
                *(short4*)&Ob[(size_t)d * SS + tb] = o;
            }
    } else {
        short* __restrict__ Ob = Vtb + (size_t)bh * HD * SS;
#pragma unroll
        for (int i = 0; i < 4; i++)
#pragma unroll
            for (int j = 0; j < 4; j++) {
                const int tb = s0 + wr + i * 16 + r0;
                const int e = wc + j * 16 + c;
                short4 o;
                o.x = f2bf(acc[i][j][0]); o.y = f2bf(acc[i][j][1]);
                o.z = f2bf(acc[i][j][2]); o.w = f2bf(acc[i][j][3]);
                *(short4*)&Ob[(size_t)e * SS + tb] = o;
            }
    }
}

// ---------------- KV: Mp[w][e][d] = V_chunk^T K'_chunk (MFMA, split-4, swizzled) ----
__global__ __launch_bounds__(256) void g_kv(
    const short* __restrict__ Vtb, const short* __restrict__ Ktb, float* __restrict__ Mp)
{
    __shared__ short As[2 * 8192], Bs[2 * 8192];
    f32x4 acc[4][4];
    const int orig = blockIdx.x;                    // 256
    const int w = (orig & 7) * 32 + (orig >> 3);
    const int chunk = w & 3, bh = w >> 2;
    gemm_tile_g(Vtb + (size_t)bh * HD * SS + chunk * 256, SS,
                Ktb + (size_t)bh * HD * SS + chunk * 256, SS, 256, As, Bs, acc);
    const int tid = threadIdx.x, lane = tid & 63, wid = tid >> 6;
    const int wr = (wid >> 1) * 64, wc = (wid & 1) * 64;
    const int r0 = (lane >> 4) * 4, c = lane & 15;
    float* __restrict__ Ob = Mp + (size_t)w * HD * HD;
#pragma unroll
    for (int i = 0; i < 4; i++)
#pragma unroll
        for (int j = 0; j < 4; j++)
#pragma unroll
            for (int r = 0; r < 4; r++)
                Ob[(size_t)(wr + i * 16 + r0 + r) * HD + wc + j * 16 + c] = acc[i][j][r];
}

// ---------------- reduce 4 chunks + cvt: Mtb[bh][e][d] bf16 ----------------
__global__ __launch_bounds__(256) void g_mredcvt(const float* __restrict__ Mp, short* __restrict__ Mtb) {
    const size_t i = ((size_t)blockIdx.x * 256 + threadIdx.x) * 8;
    const size_t bh = i >> 14, ij = i & 16383;
    const float* p = Mp + (bh * 4) * 16384 + ij;
    float s[8];
#pragma unroll
    for (int q = 0; q < 8; q++) s[q] = 0.f;
#pragma unroll
    for (int cth = 0; cth < 4; cth++) {
        float4 a = *(const float4*)&p[cth * 16384];
        float4 b = *(const float4*)&p[cth * 16384 + 4];
        s[0] += a.x; s[1] += a.y; s[2] += a.z; s[3] += a.w;
        s[4] += b.x; s[5] += b.y; s[6] += b.z; s[7] += b.w;
    }
    bf16x8 v;
#pragma unroll
    for (int q = 0; q < 8; q++) v[q] = f2bf(s[q]);
    *(bf16x8*)&Mtb[i] = v;
}

// ---------- QM: retc[b*S+s][h*128+e] = Q' @ M + fused group-stat atomics ----------
__global__ __launch_bounds__(256) void g_qm(
    const short* __restrict__ Qb, const short* __restrict__ Mtb,
    short* __restrict__ retc, float* __restrict__ Sp)
{
    __shared__ short As[2 * 8192], Bs[2 * 8192];
    f32x4 acc[4][4];
    const int orig = blockIdx.x;                    // 512
    const int w = (orig & 7) * 64 + (orig >> 3);
    const int bh = w >> 3, m0 = (w & 7) * 128;
    gemm_tile_g(Qb + ((size_t)bh * SS + m0) * HD, HD,
                Mtb + (size_t)bh * HD * HD, HD, HD, As, Bs, acc);
    const int tid = threadIdx.x, lane = tid & 63, wid = tid >> 6;
    const int wr = (wid >> 1) * 64, wc = (wid & 1) * 64;
    const int r0 = (lane >> 4) * 4, c = lane & 15;
    const int b_ = bh >> 3, h_ = bh & 7;
    short* __restrict__ O = retc + ((size_t)(b_ * SS + m0)) * DD + h_ * HD;
#pragma unroll
    for (int i = 0; i < 4; i++)
#pragma unroll
        for (int j = 0; j < 4; j++)
#pragma unroll
            for (int r = 0; r < 4; r++)
                O[(size_t)(wr + i * 16 + r0 + r) * DD + wc + j * 16 + c] = f2bf(acc[i][j][r]);

    // fused group stats: reduce over lane bits {0,1,2} and {4,5}: masks {1,2,4,16,32}
    float psm[4], psq[4];
#pragma unroll
    for (int j = 0; j < 4; j++) { psm[j] = 0.f; psq[j] = 0.f; }
#pragma unroll
    for (int i = 0; i < 4; i++)
#pragma unroll
        for (int j = 0; j < 4; j++)
#pragma unroll
            for (int r = 0; r < 4; r++) {
                const float v = acc[i][j][r];
                psm[j] += v; psq[j] += v * v;
            }
    const int masks[5] = {1, 2, 4, 16, 32};
#pragma unroll
    for (int mk = 0; mk < 5; mk++) {
#pragma unroll
        for (int j = 0; j < 4; j++) {
            psm[j] += __shfl_xor(psm[j], masks[mk], 64);
            psq[j] += __shfl_xor(psq[j], masks[mk], 64);
        }
    }
    if ((lane & 7) == 0 && lane < 16) {
        const int hi = lane >> 3;
#pragma unroll
        for (int j = 0; j < 4; j++) {
            const int g = b_ * 128 + h_ * 16 + (wid & 1) * 8 + j * 2 + hi;
            atomicAdd(&Sp[g * 2 + 0], psm[j]);
            atomicAdd(&Sp[g * 2 + 1], psq[j]);
        }
    }
}

// ---------------- aprep: Ab = gateb ⊙ GN(retc) -> bf16 ----------------
__global__ __launch_bounds__(256) void aprep(
    const short* __restrict__ gateb, const short* __restrict__ retc,
    const float* __restrict__ Sp,
    const float* __restrict__ gng, const float* __restrict__ gnb, short* __restrict__ Ab)
{
    const size_t idx = ((size_t)blockIdx.x * 256 + threadIdx.x) * 4;
    const int m = (int)(idx >> 10), cc = (int)(idx & 1023);
    const int b_ = m >> 10, g = b_ * 128 + (cc >> 3);
    const float sm = Sp[g * 2 + 0], sq = Sp[g * 2 + 1];
    const float mu = sm * (1.0f / 8192.0f);
    float var = sq * (1.0f / 8192.0f) - mu * mu;
    if (var < 0.f) var = 0.f;
    const float rs = rsqrtf(var + GN_EPS);
    short4 gv4 = *(const short4*)&gateb[idx];
    short4 rv4 = *(const short4*)&retc[idx];
    float4 gv = *(const float4*)&gng[cc];
    float4 bv = *(const float4*)&gnb[cc];
    short4 o;
    o.x = f2bf(bf2f(gv4.x) * ((bf2f(rv4.x) - mu) * rs * gv.x + bv.x));
    o.y = f2bf(bf2f(gv4.y) * ((bf2f(rv4.y) - mu) * rs * gv.y + bv.y));
    o.z = f2bf(bf2f(gv4.z) * ((bf2f(rv4.z) - mu) * rs * gv.z + bv.z));
    o.w = f2bf(bf2f(gv4.w) * ((bf2f(rv4.w) - mu) * rs * gv.w + bv.w));
    *(short4*)&Ab[idx] = o;
}

// ---------------- final GEMM: out = Ab @ WoT^T (MFMA, f32 out, XCD-chunked) ---------
__global__ __launch_bounds__(256) void g_final(
    const short* __restrict__ Ab, const short* __restrict__ WoT, float* __restrict__ out)
{
    __shared__ short As[2 * 8192], Bs[2 * 8192];
    f32x4 acc[4][4];
    const int orig = blockIdx.x;                    // 512
    const int w = (orig & 7) * 64 + (orig >> 3);
    const int m0 = (w >> 3) * 128, n0 = (w & 7) * 128;
    gemm_tile_g(Ab + (size_t)m0 * DD, DD, WoT + (size_t)n0 * DD, DD, DD, As, Bs, acc);
    const int tid = threadIdx.x, lane = tid & 63, wid = tid >> 6;
    const int wr = (wid >> 1) * 64, wc = (wid & 1) * 64;
    const int r0 = (lane >> 4) * 4, c = lane & 15;
#pragma unroll
    for (int i = 0; i < 4; i++)
#pragma unroll
        for (int j = 0; j < 4; j++)
#pragma unroll
            for (int r = 0; r < 4; r++)
                out[(size_t)(m0 + wr + i * 16 + r0 + r) * DD + n0 + wc + j * 16 + c] = acc[i][j][r];
}

extern "C" void kernel_launch(void* const* d_in, const int* in_sizes, int n_in,
                              void* d_out, int out_size, void* d_ws, size_t ws_size,
                              hipStream_t stream)
{
    const float* x   = (const float*)d_in[0];
    const float* Wq  = (const float*)d_in[1];
    const float* Wk  = (const float*)d_in[2];
    const float* Wv  = (const float*)d_in[3];
    const float* Wg  = (const float*)d_in[4];
    const float* Wo  = (const float*)d_in[5];
    const float* gng = (const float*)d_in[6];
    const float* gnb = (const float*)d_in[7];
    float* out = (float*)d_out;

    char* ws = (char*)d_ws;
    size_t off = 0;
    auto alloc = [&](size_t bytes) -> void* {
        void* p = ws + off;
        off += (bytes + 255) & ~(size_t)255;
        return p;
    };
    const size_t NE = (size_t)BB * SS * DD;   // 8,388,608
    float*  sQ    = (float*)alloc((size_t)HH * SS * sizeof(float));
    float*  sK    = (float*)alloc((size_t)HH * SS * sizeof(float));
    short*  xb    = (short*)alloc(NE * sizeof(short));
    short*  WgT   = (short*)alloc((size_t)DD * DD * sizeof(short));
    short*  WoT   = (short*)alloc((size_t)DD * DD * sizeof(short));
    short*  Wt    = (short*)alloc((size_t)24 * HD * HD * sizeof(short));
    short*  Qb    = (short*)alloc(NE * sizeof(short));
    short*  Ktb   = (short*)alloc(NE * sizeof(short));
    short*  Vtb   = (short*)alloc(NE * sizeof(short));
    short*  retc  = (short*)alloc(NE * sizeof(short));
    short*  gateb = (short*)alloc(NE * sizeof(short));
    short*  Ab    = (short*)alloc(NE * sizeof(short));
    float*  Mp    = (float*)alloc((size_t)256 * HD * HD * sizeof(float));
    short*  Mtb   = (short*)alloc((size_t)64 * HD * HD * sizeof(short));
    float*  Sp    = (float*)alloc((size_t)1024 * 2 * sizeof(float));

    prep<<<dim3(6561), 256, 0, stream>>>(x, Wq, Wk, Wv, Wg, Wo, xb, WgT, WoT, Wt, sQ, sK, Sp);
    g_qkvgate<<<dim3(2048), 256, 0, stream>>>(xb, Wt, WgT, sQ, sK, Qb, Ktb, Vtb, gateb);
    g_kv<<<dim3(256), 256, 0, stream>>>(Vtb, Ktb, Mp);
    g_mredcvt<<<dim3(512), 256, 0, stream>>>(Mp, Mtb);
    g_qm<<<dim3(512), 256, 0, stream>>>(Qb, Mtb, retc, Sp);
    aprep<<<dim3(8192), 256, 0, stream>>>(gateb, retc, Sp, gng, gnb, Ab);
    g_final<<<dim3(512), 256, 0, stream>>>(Ab, WoT, out);
}

// Round 11
// 116.592 us; speedup vs baseline: 5.9003x; 1.1064x over previous
//
#include <hip/hip_runtime.h>

#define BB 8
#define SS 1024
#define DD 1024
#define HH 8
#define HD 128
#define GN_EPS 1e-3f

typedef __attribute__((ext_vector_type(8))) short bf16x8;
typedef __attribute__((ext_vector_type(4))) float f32x4;

__device__ __forceinline__ short f2bf(float f) {
    unsigned u = __float_as_uint(f);
    return (short)((u + 0x7fffu + ((u >> 16) & 1u)) >> 16);
}
__device__ __forceinline__ float bf2f(short s) {
    return __uint_as_float(((unsigned)(unsigned short)s) << 16);
}

__device__ __forceinline__ void gload16(const void* g, void* l) {
    __builtin_amdgcn_global_load_lds((const __attribute__((address_space(1))) void*)g,
                                     (__attribute__((address_space(3))) void*)l, 16, 0, 0);
}

// ---- stage one 128x64-short tile (16 KB) via global_load_lds, 8 waves ----
// LDS: linear [row][8 chunks of 8 shorts], 128 B/row. Chunk-swizzled content:
// slot q of row r holds GLOBAL chunk q ^ (r&7) (pre-swizzled global source;
// gload_lds dest stays linear). Read side applies the same XOR.
__device__ __forceinline__ void stage_tile(const short* __restrict__ G, size_t ld, int k0,
                                           short* lds, int wid, int lane) {
#pragma unroll
    for (int i = 0; i < 2; i++) {
        const int seg = wid * 2 + i;                 // 0..15 (8 rows each)
        const int row = seg * 8 + (lane >> 3);       // 0..127
        const int chunk = (lane & 7) ^ (lane >> 3);  // slot ^ (row&7)
        gload16(G + (size_t)row * ld + k0 + chunk * 8, lds + seg * 512);
    }
}

// ------------- 128x128xK MFMA tile core: 8 waves, BK=64, gload_lds, dbuf -------------
// A: [128 rows][K] k-contig bf16 ; B: [128 cols][K] k-contig bf16
// Wave wid: rows wr=(wid>>2)*64, cols wc=(wid&3)*32. acc[4][2] (64x32 per wave).
__device__ __forceinline__ void gemm_tile_g(
    const short* __restrict__ A, size_t ldA,
    const short* __restrict__ B, size_t ldB,
    int K, short* As, short* Bs, f32x4 acc[4][2])
{
    const int tid = threadIdx.x, lane = tid & 63, wid = tid >> 6;
    const int wr = (wid >> 2) * 64, wc = (wid & 3) * 32;
    const int fr = lane & 15, fc = lane >> 4;        // fc: 16B-chunk base (0..3)
    const int rsw = fr & 7;
#pragma unroll
    for (int i = 0; i < 4; i++)
#pragma unroll
        for (int j = 0; j < 2; j++) acc[i][j] = (f32x4){0.f, 0.f, 0.f, 0.f};

    stage_tile(A, ldA, 0, As, wid, lane);
    stage_tile(B, ldB, 0, Bs, wid, lane);
    __syncthreads();
    const int nt = K >> 6;
    int cur = 0;
    for (int t = 0; t < nt; t++) {
        if (t + 1 < nt) {
            stage_tile(A, ldA, (t + 1) << 6, As + ((cur ^ 1) << 13), wid, lane);
            stage_tile(B, ldB, (t + 1) << 6, Bs + ((cur ^ 1) << 13), wid, lane);
        }
        const short* as = As + (cur << 13);
        const short* bs = Bs + (cur << 13);
#pragma unroll
        for (int half = 0; half < 2; half++) {
            const int slot = ((half * 4 + fc) ^ rsw) << 3;   // swizzled 8-short slot
            bf16x8 af[4], bfv[2];
#pragma unroll
            for (int i = 0; i < 4; i++) af[i] = *(const bf16x8*)&as[(wr + i * 16 + fr) * 64 + slot];
#pragma unroll
            for (int j = 0; j < 2; j++) bfv[j] = *(const bf16x8*)&bs[(wc + j * 16 + fr) * 64 + slot];
#pragma unroll
            for (int i = 0; i < 4; i++)
#pragma unroll
                for (int j = 0; j < 2; j++)
                    acc[i][j] = __builtin_amdgcn_mfma_f32_16x16x32_bf16(af[i], bfv[j], acc[i][j], 0, 0, 0);
        }
        __syncthreads();
        cur ^= 1;
    }
}

// ---------------- prep: x->bf16, W transposes, scales, zero Sp ----------------
__global__ __launch_bounds__(256) void prep(
    const float* __restrict__ x,
    const float* __restrict__ Wq, const float* __restrict__ Wk, const float* __restrict__ Wv,
    const float* __restrict__ Wg, const float* __restrict__ Wo,
    short* __restrict__ xb, short* __restrict__ WgT, short* __restrict__ WoT,
    short* __restrict__ Wt, float* __restrict__ sQ, float* __restrict__ sK,
    float* __restrict__ Sp)
{
    __shared__ float t[32][33];
    int bid = blockIdx.x;
    const int tid = threadIdx.x;
    if (bid < 4096) {                       // x -> bf16 flat
        const size_t i = ((size_t)bid * 256 + tid) * 8;
        float4 a = *(const float4*)&x[i];
        float4 b = *(const float4*)&x[i + 4];
        bf16x8 v;
        v[0] = f2bf(a.x); v[1] = f2bf(a.y); v[2] = f2bf(a.z); v[3] = f2bf(a.w);
        v[4] = f2bf(b.x); v[5] = f2bf(b.y); v[6] = f2bf(b.z); v[7] = f2bf(b.w);
        *(bf16x8*)&xb[i] = v;
        return;
    }
    bid -= 4096;
    if (bid < 2048) {                       // Wg / Wo transpose -> bf16
        const float* __restrict__ S = (bid < 1024) ? Wg : Wo;
        short* __restrict__ D = (bid < 1024) ? WgT : WoT;
        const int tb = bid & 1023;
        const int bx = (tb & 31) * 32, by = (tb >> 5) * 32;
        const int xx = tid & 31, y0 = tid >> 5;
#pragma unroll
        for (int r = 0; r < 32; r += 8) t[y0 + r][xx] = S[(size_t)(by + y0 + r) * 1024 + bx + xx];
        __syncthreads();
#pragma unroll
        for (int r = 0; r < 32; r += 8) D[(size_t)(bx + y0 + r) * 1024 + by + xx] = f2bf(t[xx][y0 + r]);
        return;
    }
    bid -= 2048;
    if (bid < 384) {                        // 24 head matrices
        const int ht = bid >> 4, tb = bid & 15;
        const int typ = ht >> 3, h = ht & 7;
        const float* __restrict__ W = (typ == 0 ? Wq : (typ == 1 ? Wk : Wv)) + (size_t)h * HD * HD;
        short* __restrict__ D = Wt + (size_t)ht * HD * HD;
        const int bx = (tb & 3) * 32, by = (tb >> 2) * 32;
        const int xx = tid & 31, y0 = tid >> 5;
#pragma unroll
        for (int r = 0; r < 32; r += 8) t[y0 + r][xx] = W[(by + y0 + r) * HD + bx + xx];
        __syncthreads();
#pragma unroll
        for (int r = 0; r < 32; r += 8) D[(bx + y0 + r) * HD + by + xx] = f2bf(t[xx][y0 + r]);
        return;
    }
    bid -= 384;
    if (bid < 32) {                         // decay scale tables
        const int h = bid >> 2;
        const int s = (bid & 3) * 256 + tid;
        const double gamma = 1.0 - exp2((double)(-5 - h));
        const double lg = log2(gamma);
        sQ[h * SS + s] = (float)exp2(lg * (double)s);
        sK[h * SS + s] = (float)exp2(-lg * (double)s);
        return;
    }
    // last block: zero Sp[2048]
    *(float4*)&Sp[tid * 8] = (float4){0.f, 0.f, 0.f, 0.f};
    *(float4*)&Sp[tid * 8 + 4] = (float4){0.f, 0.f, 0.f, 0.f};
}

// ---- QKV + gate GEMM in one dispatch (2048 blocks x 512 thr, XCD-chunked) ----
__global__ __launch_bounds__(512) void g_qkvgate(
    const short* __restrict__ xb, const short* __restrict__ Wt, const short* __restrict__ WgT,
    const float* __restrict__ sQ, const float* __restrict__ sK,
    short* __restrict__ Qb, short* __restrict__ Ktb, short* __restrict__ Vtb,
    short* __restrict__ gateb)
{
    __shared__ short As[2 * 8192], Bs[2 * 8192];
    f32x4 acc[4][2];
    const int orig = blockIdx.x;
    const int cx = orig & 7, p = orig >> 3;
    const int tid = threadIdx.x, lane = tid & 63, wid = tid >> 6;
    const int wr = (wid >> 2) * 64, wc = (wid & 3) * 32;
    const int r0 = (lane >> 4) * 4, c = lane & 15;

    if (p < 64) {
        // gate GEMM: gateb = ReLU(xb @ WgT^T) bf16
        const int w2 = cx * 64 + p;
        const int m0 = (w2 >> 3) * 128, n0 = (w2 & 7) * 128;
        gemm_tile_g(xb + (size_t)m0 * DD, DD, WgT + (size_t)n0 * DD, DD, DD, As, Bs, acc);
#pragma unroll
        for (int i = 0; i < 4; i++)
#pragma unroll
            for (int j = 0; j < 2; j++)
#pragma unroll
                for (int r = 0; r < 4; r++)
                    gateb[(size_t)(m0 + wr + i * 16 + r0 + r) * DD + n0 + wc + j * 16 + c] =
                        f2bf(fmaxf(acc[i][j][r], 0.f));
        return;
    }
    // QKV
    const int w = cx * 192 + (p - 64);
    const int ht = w >> 6, mt = w & 63;
    const int m0 = mt * 128;
    const int typ = ht >> 3, h = ht & 7;
    gemm_tile_g(xb + (size_t)m0 * DD + h * HD, DD,
                Wt + (size_t)ht * HD * HD, HD, HD, As, Bs, acc);
    const int b = m0 >> 10, s0 = m0 & (SS - 1);
    const int bh = (b << 3) + h;
    if (typ == 0) {
#pragma unroll
        for (int i = 0; i < 4; i++)
#pragma unroll
            for (int j = 0; j < 2; j++)
#pragma unroll
                for (int r = 0; r < 4; r++) {
                    const int s = s0 + wr + i * 16 + r0 + r;
                    Qb[((size_t)bh * SS + s) * HD + wc + j * 16 + c] =
                        f2bf(acc[i][j][r] * sQ[h * SS + s]);
                }
    } else if (typ == 1) {
        short* __restrict__ Ob = Ktb + (size_t)bh * HD * SS;
#pragma unroll
        for (int i = 0; i < 4; i++)
#pragma unroll
            for (int j = 0; j < 2; j++) {
                const int tb = s0 + wr + i * 16 + r0;
                const int d = wc + j * 16 + c;
                short4 o;
                o.x = f2bf(acc[i][j][0] * sK[h * SS + tb + 0]);
                o.y = f2bf(acc[i][j][1] * sK[h * SS + tb + 1]);
                o.z = f2bf(acc[i][j][2] * sK[h * SS + tb + 2]);
                o.w = f2bf(acc[i][j][3] * sK[h * SS + tb + 3]);
                *(short4*)&Ob[(size_t)d * SS + tb] = o;
            }
    } else {
        short* __restrict__ Ob = Vtb + (size_t)bh * HD * SS;
#pragma unroll
        for (int i = 0; i < 4; i++)
#pragma unroll
            for (int j = 0; j < 2; j++) {
                const int tb = s0 + wr + i * 16 + r0;
                const int e = wc + j * 16 + c;
                short4 o;
                o.x = f2bf(acc[i][j][0]); o.y = f2bf(acc[i][j][1]);
                o.z = f2bf(acc[i][j][2]); o.w = f2bf(acc[i][j][3]);
                *(short4*)&Ob[(size_t)e * SS + tb] = o;
            }
    }
}

// ---------------- KV: Mp[w][e][d] = V_chunk^T K'_chunk (split-4, swizzled) ----------
__global__ __launch_bounds__(512) void g_kv(
    const short* __restrict__ Vtb, const short* __restrict__ Ktb, float* __restrict__ Mp)
{
    __shared__ short As[2 * 8192], Bs[2 * 8192];
    f32x4 acc[4][2];
    const int orig = blockIdx.x;                    // 256
    const int w = (orig & 7) * 32 + (orig >> 3);
    const int chunk = w & 3, bh = w >> 2;
    gemm_tile_g(Vtb + (size_t)bh * HD * SS + chunk * 256, SS,
                Ktb + (size_t)bh * HD * SS + chunk * 256, SS, 256, As, Bs, acc);
    const int tid = threadIdx.x, lane = tid & 63, wid = tid >> 6;
    const int wr = (wid >> 2) * 64, wc = (wid & 3) * 32;
    const int r0 = (lane >> 4) * 4, c = lane & 15;
    float* __restrict__ Ob = Mp + (size_t)w * HD * HD;
#pragma unroll
    for (int i = 0; i < 4; i++)
#pragma unroll
        for (int j = 0; j < 2; j++)
#pragma unroll
            for (int r = 0; r < 4; r++)
                Ob[(size_t)(wr + i * 16 + r0 + r) * HD + wc + j * 16 + c] = acc[i][j][r];
}

// ---------------- reduce 4 chunks + cvt: Mtb[bh][e][d] bf16 ----------------
__global__ __launch_bounds__(256) void g_mredcvt(const float* __restrict__ Mp, short* __restrict__ Mtb) {
    const size_t i = ((size_t)blockIdx.x * 256 + threadIdx.x) * 8;
    const size_t bh = i >> 14, ij = i & 16383;
    const float* p = Mp + (bh * 4) * 16384 + ij;
    float s[8];
#pragma unroll
    for (int q = 0; q < 8; q++) s[q] = 0.f;
#pragma unroll
    for (int cth = 0; cth < 4; cth++) {
        float4 a = *(const float4*)&p[cth * 16384];
        float4 b = *(const float4*)&p[cth * 16384 + 4];
        s[0] += a.x; s[1] += a.y; s[2] += a.z; s[3] += a.w;
        s[4] += b.x; s[5] += b.y; s[6] += b.z; s[7] += b.w;
    }
    bf16x8 v;
#pragma unroll
    for (int q = 0; q < 8; q++) v[q] = f2bf(s[q]);
    *(bf16x8*)&Mtb[i] = v;
}

// ---------- QM: retc[b*S+s][h*128+e] = Q' @ M + fused group-stat atomics ----------
__global__ __launch_bounds__(512) void g_qm(
    const short* __restrict__ Qb, const short* __restrict__ Mtb,
    short* __restrict__ retc, float* __restrict__ Sp)
{
    __shared__ short As[2 * 8192], Bs[2 * 8192];
    f32x4 acc[4][2];
    const int orig = blockIdx.x;                    // 512
    const int w = (orig & 7) * 64 + (orig >> 3);
    const int bh = w >> 3, m0 = (w & 7) * 128;
    gemm_tile_g(Qb + ((size_t)bh * SS + m0) * HD, HD,
                Mtb + (size_t)bh * HD * HD, HD, HD, As, Bs, acc);
    const int tid = threadIdx.x, lane = tid & 63, wid = tid >> 6;
    const int wr = (wid >> 2) * 64, wc = (wid & 3) * 32;
    const int r0 = (lane >> 4) * 4, c = lane & 15;
    const int b_ = bh >> 3, h_ = bh & 7;
    short* __restrict__ O = retc + ((size_t)(b_ * SS + m0)) * DD + h_ * HD;
#pragma unroll
    for (int i = 0; i < 4; i++)
#pragma unroll
        for (int j = 0; j < 2; j++)
#pragma unroll
            for (int r = 0; r < 4; r++)
                O[(size_t)(wr + i * 16 + r0 + r) * DD + wc + j * 16 + c] = f2bf(acc[i][j][r]);

    // fused group stats: reduce over lane bits {0,1,2} (cols within group-of-8)
    // and {4,5} (row groups): masks {1,2,4,16,32}. Lane bit 3 = column-group half.
    float psm[2], psq[2];
#pragma unroll
    for (int j = 0; j < 2; j++) { psm[j] = 0.f; psq[j] = 0.f; }
#pragma unroll
    for (int i = 0; i < 4; i++)
#pragma unroll
        for (int j = 0; j < 2; j++)
#pragma unroll
            for (int r = 0; r < 4; r++) {
                const float v = acc[i][j][r];
                psm[j] += v; psq[j] += v * v;
            }
    const int masks[5] = {1, 2, 4, 16, 32};
#pragma unroll
    for (int mk = 0; mk < 5; mk++) {
#pragma unroll
        for (int j = 0; j < 2; j++) {
            psm[j] += __shfl_xor(psm[j], masks[mk], 64);
            psq[j] += __shfl_xor(psq[j], masks[mk], 64);
        }
    }
    if ((lane & 7) == 0 && lane < 16) {      // lanes 0 (hi=0) and 8 (hi=1)
        const int hi = lane >> 3;
#pragma unroll
        for (int j = 0; j < 2; j++) {
            const int g = b_ * 128 + h_ * 16 + (wid & 3) * 4 + j * 2 + hi;
            atomicAdd(&Sp[g * 2 + 0], psm[j]);
            atomicAdd(&Sp[g * 2 + 1], psq[j]);
        }
    }
}

// ---------------- aprep: Ab = gateb ⊙ GN(retc) -> bf16 ----------------
__global__ __launch_bounds__(256) void aprep(
    const short* __restrict__ gateb, const short* __restrict__ retc,
    const float* __restrict__ Sp,
    const float* __restrict__ gng, const float* __restrict__ gnb, short* __restrict__ Ab)
{
    const size_t idx = ((size_t)blockIdx.x * 256 + threadIdx.x) * 4;
    const int m = (int)(idx >> 10), cc = (int)(idx & 1023);
    const int b_ = m >> 10, g = b_ * 128 + (cc >> 3);
    const float sm = Sp[g * 2 + 0], sq = Sp[g * 2 + 1];
    const float mu = sm * (1.0f / 8192.0f);
    float var = sq * (1.0f / 8192.0f) - mu * mu;
    if (var < 0.f) var = 0.f;
    const float rs = rsqrtf(var + GN_EPS);
    short4 gv4 = *(const short4*)&gateb[idx];
    short4 rv4 = *(const short4*)&retc[idx];
    float4 gv = *(const float4*)&gng[cc];
    float4 bv = *(const float4*)&gnb[cc];
    short4 o;
    o.x = f2bf(bf2f(gv4.x) * ((bf2f(rv4.x) - mu) * rs * gv.x + bv.x));
    o.y = f2bf(bf2f(gv4.y) * ((bf2f(rv4.y) - mu) * rs * gv.y + bv.y));
    o.z = f2bf(bf2f(gv4.z) * ((bf2f(rv4.z) - mu) * rs * gv.z + bv.z));
    o.w = f2bf(bf2f(gv4.w) * ((bf2f(rv4.w) - mu) * rs * gv.w + bv.w));
    *(short4*)&Ab[idx] = o;
}

// ---------------- final GEMM: out = Ab @ WoT^T (f32 out, XCD-chunked) ---------------
__global__ __launch_bounds__(512) void g_final(
    const short* __restrict__ Ab, const short* __restrict__ WoT, float* __restrict__ out)
{
    __shared__ short As[2 * 8192], Bs[2 * 8192];
    f32x4 acc[4][2];
    const int orig = blockIdx.x;                    // 512
    const int w = (orig & 7) * 64 + (orig >> 3);
    const int m0 = (w >> 3) * 128, n0 = (w & 7) * 128;
    gemm_tile_g(Ab + (size_t)m0 * DD, DD, WoT + (size_t)n0 * DD, DD, DD, As, Bs, acc);
    const int tid = threadIdx.x, lane = tid & 63, wid = tid >> 6;
    const int wr = (wid >> 2) * 64, wc = (wid & 3) * 32;
    const int r0 = (lane >> 4) * 4, c = lane & 15;
#pragma unroll
    for (int i = 0; i < 4; i++)
#pragma unroll
        for (int j = 0; j < 2; j++)
#pragma unroll
            for (int r = 0; r < 4; r++)
                out[(size_t)(m0 + wr + i * 16 + r0 + r) * DD + n0 + wc + j * 16 + c] = acc[i][j][r];
}

extern "C" void kernel_launch(void* const* d_in, const int* in_sizes, int n_in,
                              void* d_out, int out_size, void* d_ws, size_t ws_size,
                              hipStream_t stream)
{
    const float* x   = (const float*)d_in[0];
    const float* Wq  = (const float*)d_in[1];
    const float* Wk  = (const float*)d_in[2];
    const float* Wv  = (const float*)d_in[3];
    const float* Wg  = (const float*)d_in[4];
    const float* Wo  = (const float*)d_in[5];
    const float* gng = (const float*)d_in[6];
    const float* gnb = (const float*)d_in[7];
    float* out = (float*)d_out;

    char* ws = (char*)d_ws;
    size_t off = 0;
    auto alloc = [&](size_t bytes) -> void* {
        void* p = ws + off;
        off += (bytes + 255) & ~(size_t)255;
        return p;
    };
    const size_t NE = (size_t)BB * SS * DD;   // 8,388,608
    float*  sQ    = (float*)alloc((size_t)HH * SS * sizeof(float));
    float*  sK    = (float*)alloc((size_t)HH * SS * sizeof(float));
    short*  xb    = (short*)alloc(NE * sizeof(short));
    short*  WgT   = (short*)alloc((size_t)DD * DD * sizeof(short));
    short*  WoT   = (short*)alloc((size_t)DD * DD * sizeof(short));
    short*  Wt    = (short*)alloc((size_t)24 * HD * HD * sizeof(short));
    short*  Qb    = (short*)alloc(NE * sizeof(short));
    short*  Ktb   = (short*)alloc(NE * sizeof(short));
    short*  Vtb   = (short*)alloc(NE * sizeof(short));
    short*  retc  = (short*)alloc(NE * sizeof(short));
    short*  gateb = (short*)alloc(NE * sizeof(short));
    short*  Ab    = (short*)alloc(NE * sizeof(short));
    float*  Mp    = (float*)alloc((size_t)256 * HD * HD * sizeof(float));
    short*  Mtb   = (short*)alloc((size_t)64 * HD * HD * sizeof(short));
    float*  Sp    = (float*)alloc((size_t)1024 * 2 * sizeof(float));

    prep<<<dim3(6561), 256, 0, stream>>>(x, Wq, Wk, Wv, Wg, Wo, xb, WgT, WoT, Wt, sQ, sK, Sp);
    g_qkvgate<<<dim3(2048), 512, 0, stream>>>(xb, Wt, WgT, sQ, sK, Qb, Ktb, Vtb, gateb);
    g_kv<<<dim3(256), 512, 0, stream>>>(Vtb, Ktb, Mp);
    g_mredcvt<<<dim3(512), 256, 0, stream>>>(Mp, Mtb);
    g_qm<<<dim3(512), 512, 0, stream>>>(Qb, Mtb, retc, Sp);
    aprep<<<dim3(8192), 256, 0, stream>>>(gateb, retc, Sp, gng, gnb, Ab);
    g_final<<<dim3(512), 512, 0, stream>>>(Ab, WoT, out);
}